// Round 12
// baseline (786.177 us; speedup 1.0000x reference)
//
#include <hip/hip_runtime.h>
#include <stdint.h>

// Problem constants
#define N_VOX    200000
#define C_CH     64
#define K_OFF    27
#define M_PAIRS  100000
#define KM       (K_OFF * M_PAIRS)          // 2,700,000 pairs
#define TILE     64                         // output voxels per tile (o>>6)
#define NT       (N_VOX / TILE)             // 3125 tiles exactly
#define NB       (NT * K_OFF)               // 84375 (tile,k) buckets
#define WBN      (K_OFF * 4096)             // 110592 weight elems per layer
#define EPS_BN   1e-5f
#define CDCAP    (KM / 16 + NB + 64)        // max total chunks

// slice decomposition (atomic-free sort)
#define SLICES   16
#define SLICE_LEN (M_PAIRS / SLICES)        // 6250
#define KB       (K_OFF * SLICES)           // 432
#define PTS      3200                       // plane stride (3125 padded)

// hierarchical scan geometry
#define SCHUNK   2048
#define NBLK1    ((NB + SCHUNK - 1) / SCHUNK)   // 42
#define PQ1      0
#define PQ2      128

// reduce capacity (rows per tile; mean 864, sigma ~29 -> 1536 is ~23 sigma)
#define RCAP     1536

typedef __attribute__((ext_vector_type(8))) short   short8_t;  // 8 x bf16
typedef __attribute__((ext_vector_type(4))) float   f32x4;

__device__ __forceinline__ unsigned short f2bf(float f) {
    union { float f; unsigned u; } v; v.f = f;
    unsigned r = v.u + 0x7FFFu + ((v.u >> 16) & 1u);   // RTNE
    return (unsigned short)(r >> 16);
}
__device__ __forceinline__ float bf2f(unsigned u16) {
    union { unsigned u; float f; } v; v.u = u16 << 16;
    return v.f;
}
// position-layout channel index -> standard channel
__device__ __forceinline__ int pmap(int cs) {
    int p = cs >> 1, h = cs & 1;
    return (p & 3) * 16 + (p >> 2) * 2 + h;
}

// ---------- prep: xb convert (8-wide), w1 (std) / w2 (PMAP-Cin) B-frag swizzle, BN fold ----------
__global__ void prep_kernel(const float* __restrict__ x,
                            const float* __restrict__ w1, const float* __restrict__ w2,
                            const float* __restrict__ g1, const float* __restrict__ b1,
                            const float* __restrict__ m1, const float* __restrict__ v1,
                            const float* __restrict__ g2, const float* __restrict__ b2,
                            const float* __restrict__ m2, const float* __restrict__ v2,
                            unsigned short* __restrict__ xb,
                            unsigned short* __restrict__ wb1, unsigned short* __restrict__ wb2,
                            float* __restrict__ sbp1, float* __restrict__ sbp2)
{
    long i = (long)blockIdx.x * blockDim.x + threadIdx.x;
    const long XBN8 = (long)N_VOX * C_CH / 8;   // 1.6M
    if (i < XBN8) {
        const f32x4* sp = (const f32x4*)(x + (size_t)i * 8);
        f32x4 a = sp[0], b = sp[1];
        uint4 o;
        o.x = (unsigned)f2bf(a[0]) | ((unsigned)f2bf(a[1]) << 16);
        o.y = (unsigned)f2bf(a[2]) | ((unsigned)f2bf(a[3]) << 16);
        o.z = (unsigned)f2bf(b[0]) | ((unsigned)f2bf(b[1]) << 16);
        o.w = (unsigned)f2bf(b[2]) | ((unsigned)f2bf(b[3]) << 16);
        ((uint4*)xb)[i] = o;
        return;
    }
    long j = i - XBN8;
    if (j < 2 * WBN) {
        int isw2 = j >= WBN;
        int o = (int)(isw2 ? j - WBN : j);
        int k   = o >> 12;
        int rem = o & 4095;
        int t  = rem >> 11;
        int sl = (rem >> 9) & 3;
        int d  = (rem >> 3) & 63;
        int jj = rem & 7;
        int cs = t * 32 + sl * 8 + jj;      // A k-slot
        if (!isw2) wb1[o] = f2bf(w1[k * 4096 + cs * 64 + d]);
        else       wb2[o] = f2bf(w2[k * 4096 + pmap(cs) * 64 + d]);  // hb is position-permuted
        return;
    }
    j -= 2 * WBN;
    if (j < 128) {
        int L = (int)(j >= 64);
        int ch = (int)(j & 63);
        float gv = L ? g2[ch] : g1[ch];
        float vv = L ? v2[ch] : v1[ch];
        float mv = L ? m2[ch] : m1[ch];
        float bv = L ? b2[ch] : b1[ch];
        float s = gv * rsqrtf(vv + EPS_BN);
        float sh = bv - mv * s;
        int n = ch >> 4, rem = ch & 15, m = rem >> 1, h = rem & 1;
        int idx = 2 * (m * 4 + n) + h;      // position-layout slot
        float* sbp = L ? sbp2 : sbp1;
        sbp[idx] = s; sbp[64 + idx] = sh;
    }
}

// ---------- hist: per-(k,slice) block, LDS tile-histogram, coalesced partial write ----------
__global__ __launch_bounds__(256) void hist_kernel(const int* __restrict__ out_map,
                                                   int* __restrict__ partial)
{
    __shared__ int h[3136];
    int blk = blockIdx.x;                 // 432 = 27k x 16s
    int k = blk >> 4, s = blk & 15;
    int tid = threadIdx.x;
    for (int i = tid; i < 3136; i += 256) h[i] = 0;
    __syncthreads();
    int p0 = k * M_PAIRS + s * SLICE_LEN;
    for (int i = tid; i < SLICE_LEN; i += 256)
        atomicAdd(&h[out_map[p0 + i] >> 6], 1);
    __syncthreads();
    for (int t = tid; t < NT; t += 256)
        partial[blk * PTS + t] = h[t];
}

// ---------- transpose partial[kb][t] -> partial_T[t][kb] (LDS-tiled) ----------
__global__ __launch_bounds__(256) void transp_kernel(const int* __restrict__ partial,
                                                     int* __restrict__ partial_T)
{
    __shared__ int tb[32][33];
    int bx = blockIdx.x % 14, by = blockIdx.x / 14;
    int kb0 = bx * 32, t0 = by * 32;
    int tx = threadIdx.x & 31, ty = threadIdx.x >> 5;   // ty 0..7
    #pragma unroll
    for (int dy = 0; dy < 32; dy += 8) {
        int kb = kb0 + ty + dy;
        tb[ty + dy][tx] = (kb < KB) ? partial[kb * PTS + t0 + tx] : 0;
    }
    __syncthreads();
    #pragma unroll
    for (int dy = 0; dy < 32; dy += 8) {
        int t = t0 + ty + dy;
        int kb = kb0 + tx;
        if (t < NT && kb < KB)
            partial_T[t * KB + kb] = tb[tx][ty + dy];
    }
}

// ---------- scanA: per-2048-bucket partial sums (raw + ceil16) ----------
__global__ __launch_bounds__(256) void scanA_kernel(const int* __restrict__ partial_T,
                                                    int* __restrict__ part)
{
    __shared__ int lds[256], lds2[256];
    int b0 = blockIdx.x * SCHUNK;
    int t = threadIdx.x;
    int sraw = 0, sc16 = 0;
    for (int i = t; i < SCHUNK; i += 256) {
        int b = b0 + i;
        if (b < NB) {
            int tt = b / K_OFF, k = b % K_OFF;
            const int* pr = &partial_T[tt * KB + k * SLICES];
            int c = 0;
            #pragma unroll
            for (int s = 0; s < SLICES; ++s) c += pr[s];
            sraw += c; sc16 += (c + 15) >> 4;
        }
    }
    lds[t] = sraw; lds2[t] = sc16;
    __syncthreads();
    for (int d = 128; d > 0; d >>= 1) {
        if (t < d) { lds[t] += lds[t + d]; lds2[t] += lds2[t + d]; }
        __syncthreads();
    }
    if (t == 0) { part[PQ1 + blockIdx.x] = lds[0]; part[PQ2 + blockIdx.x] = lds2[0]; }
}

// ---------- scanB: exclusive scan of chunk partials (2 segments) ----------
__global__ __launch_bounds__(128) void scanB_kernel(int* __restrict__ part) {
    __shared__ int lds[128];
    int g = blockIdx.x, t = threadIdx.x;
    int base = (g == 0) ? PQ1 : PQ2;
    int v = (t < NBLK1) ? part[base + t] : 0;
    lds[t] = v;
    __syncthreads();
    for (int d = 1; d < 128; d <<= 1) {
        int u = (t >= d) ? lds[t - d] : 0;
        __syncthreads();
        lds[t] += u;
        __syncthreads();
    }
    if (t < NBLK1) part[base + t] = lds[t] - v;
}

// ---------- scanC: chunk-local scan + base -> offs/cdoffs; fused slice-major base table ----------
__global__ __launch_bounds__(256) void scanC_kernel(const int* __restrict__ partial_T,
                                                    const int* __restrict__ part,
                                                    int* __restrict__ offs,
                                                    int* __restrict__ cdoffs,
                                                    int* __restrict__ base)   // [(k*16+s)][t] (stride PTS)
{
    __shared__ int lds[256], lds2[256];
    int b = blockIdx.x, t = threadIdx.x;
    int i0 = b * SCHUNK + t * 8;
    int c[8]; int sraw = 0, sc16 = 0;
    #pragma unroll
    for (int j = 0; j < 8; ++j) {
        int idx = i0 + j;
        int tot = 0;
        if (idx < NB) {
            int tt = idx / K_OFF, k = idx - tt * K_OFF;
            const int* pr = &partial_T[tt * KB + k * SLICES];
            #pragma unroll
            for (int s = 0; s < SLICES; ++s) tot += pr[s];
        }
        c[j] = tot;
        sraw += tot; sc16 += (tot + 15) >> 4;
    }
    int vr = sraw, vc = sc16;
    lds[t] = vr; lds2[t] = vc;
    __syncthreads();
    for (int d = 1; d < 256; d <<= 1) {
        int ur = (t >= d) ? lds[t - d] : 0;
        int uc = (t >= d) ? lds2[t - d] : 0;
        __syncthreads();
        lds[t] += ur; lds2[t] += uc;
        __syncthreads();
    }
    int braw = part[PQ1 + b] + lds[t] - vr;
    int bc16 = part[PQ2 + b] + lds2[t] - vc;
    #pragma unroll
    for (int j = 0; j < 8; ++j) {
        int idx = i0 + j;
        if (idx < NB) {
            offs[idx] = braw; cdoffs[idx] = bc16;
            int tt = idx / K_OFF, k = idx - tt * K_OFF;
            const int* pr = &partial_T[tt * KB + k * SLICES];
            int run = braw;
            #pragma unroll
            for (int s = 0; s < SLICES; ++s) {
                base[(k * SLICES + s) * PTS + tt] = run;
                run += pr[s];
            }
        }
        braw += c[j]; bc16 += (c[j] + 15) >> 4;
    }
    if (b == NBLK1 - 1 && t == 255) { offs[NB] = braw; cdoffs[NB] = bc16; }
}

// ---------- scatter2 v2: LDS-staged base row, zero global random reads ----------
__global__ __launch_bounds__(256) void scatter2_kernel(const int* __restrict__ in_map,
                                                       const int* __restrict__ out_map,
                                                       const int* __restrict__ base,
                                                       unsigned* __restrict__ pp)
{
    __shared__ int lbase[NT];                 // 12.5 KB
    __shared__ int h2[NT];                    // 12.5 KB rank counters
    int blk = blockIdx.x;
    int k = blk >> 4, s = blk & 15;
    int tid = threadIdx.x;
    const int* gb = &base[(k * SLICES + s) * PTS];
    for (int i = tid; i < NT; i += 256) { lbase[i] = gb[i]; h2[i] = 0; }
    __syncthreads();
    int p0 = k * M_PAIRS + s * SLICE_LEN;
    #pragma unroll 2
    for (int i = tid; i < SLICE_LEN; i += 256) {
        int p = p0 + i;
        int o = out_map[p];
        int t = o >> 6;
        int rank = atomicAdd(&h2[t], 1);      // LDS-only atomic
        pp[lbase[t] + rank] = (unsigned)in_map[p] | ((unsigned)(o & 63) << 18);
    }
}

// ---------- build global chunk descriptors: k | pbase<<5 | pend<<27 ----------
__global__ void cdescb_kernel(const int* __restrict__ offs, const int* __restrict__ cdoffs,
                              unsigned long long* __restrict__ cdesc)
{
    int b = blockIdx.x * 256 + threadIdx.x;
    if (b >= NB) return;
    int k = b % K_OFF;
    int c0 = cdoffs[b];
    int nchunk = cdoffs[b + 1] - c0;
    int base = offs[b];
    int end  = offs[b + 1];
    for (int i = 0; i < nchunk; ++i)
        cdesc[c0 + i] = (unsigned long long)k
                      | ((unsigned long long)(base + 16 * i) << 5)
                      | ((unsigned long long)end << 27);
}

// ---------- computeY: one chunk per wave; gather 16 bf16 rows, 8 MFMA, repack, seq Y write ----------
__global__ __launch_bounds__(256) void computeY_kernel(
    const unsigned short* __restrict__ xin,     // bf16 rows [N][64] (xb std / hb position-layout)
    const unsigned short* __restrict__ wb,      // pre-swizzled bf16 weights
    const unsigned* __restrict__ pp,            // iidx | oloc<<18, (tile,k)-sorted
    const unsigned long long* __restrict__ cdesc,
    const int* __restrict__ csp,                // &cdoffs[tg0*27]
    const int* __restrict__ cep,                // &cdoffs[tg1*27]
    const int* __restrict__ pgb,                // &offs[tg0*27] (group pos base)
    unsigned* __restrict__ Y,                   // rows of 32 u32 (bf16 pairs, position layout)
    int ycap)
{
    int c = csp[0] + blockIdx.x * 4 + (threadIdx.x >> 6);
    if (c >= cep[0]) return;
    unsigned long long d = cdesc[c];
    int k     = (int)(d & 31);
    int pbase = (int)((d >> 5) & 0x3FFFFF);
    int pend  = (int)(d >> 27);
    int pg = pgb[0];
    int lane  = threadIdx.x & 63;
    int r     = lane & 15;
    int sfour = lane >> 4;
    int par   = lane & 1;

    int ii = pbase + r;
    bool real = ii < pend;
    unsigned pv = pp[real ? ii : pbase];
    unsigned iidx = pv & 0x3FFFFu;
    int yr;
    if (real) { yr = ii - pg; if (yr > ycap) yr = ycap; }
    else      { yr = ycap + 8 + (c & 63); }

    const short8_t* xrow = (const short8_t*)(xin + (size_t)iidx * 64);
    short8_t A0 = xrow[sfour];
    short8_t A1 = xrow[4 + sfour];
    const short8_t* wbk = (const short8_t*)(wb + k * 4096);

    f32x4 acc[4] = {{0,0,0,0},{0,0,0,0},{0,0,0,0},{0,0,0,0}};
    #pragma unroll
    for (int n = 0; n < 4; ++n) {
        acc[n] = __builtin_amdgcn_mfma_f32_16x16x32_bf16(A0, wbk[sfour * 64 + n * 16 + r], acc[n], 0, 0, 0);
        acc[n] = __builtin_amdgcn_mfma_f32_16x16x32_bf16(A1, wbk[(4 + sfour) * 64 + n * 16 + r], acc[n], 0, 0, 0);
    }

    // repack D (col=n*16+r, row=sfour*4+j) into bf16 Y rows; lane-pair exchange packs ch pairs
    #pragma unroll
    for (int jj = 0; jj < 4; jj += 2) {
        uint4 w;
        unsigned* wp = (unsigned*)&w;
        #pragma unroll
        for (int n = 0; n < 4; ++n) {
            float mine = par ? acc[n][jj + 1] : acc[n][jj];
            float send = par ? acc[n][jj]     : acc[n][jj + 1];
            float tt = __shfl_xor(send, 1, 64);
            float lo = par ? tt : mine;
            float hi = par ? mine : tt;
            wp[n] = (unsigned)f2bf(lo) | ((unsigned)f2bf(hi) << 16);
        }
        int Rw = sfour * 4 + jj + par;
        int yrow = __shfl(yr, Rw, 64);
        ((uint4*)Y)[(size_t)yrow * 8 + (r >> 1)] = w;
    }
}

// ---------- reduce v2: LDS rank/permute (int atomics only), register-sum per voxel ----------
template<int LAYER>
__global__ __launch_bounds__(256) void reduce_kernel(
    const unsigned* __restrict__ Y,
    const unsigned* __restrict__ pp,
    const int* __restrict__ offs,
    const int* __restrict__ pgb,
    const float* __restrict__ sbp,              // [0:64) scale, [64:128) shift (position order)
    const float* __restrict__ xres,             // LAYER==1 residual (std layout)
    void* __restrict__ outp,                    // L0: hb (bf16 position layout); L1: f32 std
    int tg0, int ycap)
{
    __shared__ unsigned short ridx[RCAP];
    __shared__ unsigned short rrank[RCAP];
    __shared__ unsigned char  soloc[RCAP];
    __shared__ int hist[TILE];
    __shared__ int cstart[TILE + 1];

    const int tile = tg0 + blockIdx.x;
    const int tid = threadIdx.x;
    const int p0 = offs[tile * K_OFF];
    const int p1 = offs[(tile + 1) * K_OFF];
    const int pg = pgb[0];
    int nr = p1 - p0; if (nr > RCAP) nr = RCAP;

    if (tid < TILE) hist[tid] = 0;
    __syncthreads();
    for (int i = tid; i < nr; i += 256) {
        int ol = (int)((pp[p0 + i] >> 18) & 63);
        soloc[i] = (unsigned char)ol;
        rrank[i] = (unsigned short)atomicAdd(&hist[ol], 1);   // LDS int atomic, 64 bins
    }
    __syncthreads();
    if (tid < 64) {                               // exclusive prefix of 64 bins (wave 0)
        int v = hist[tid];
        int s = v;
        #pragma unroll
        for (int d = 1; d < 64; d <<= 1) {
            int u = __shfl_up(s, d, 64);
            if (tid >= d) s += u;
        }
        cstart[tid] = s - v;
        if (tid == 63) cstart[64] = s;
    }
    __syncthreads();
    for (int i = tid; i < nr; i += 256)
        ridx[cstart[soloc[i]] + rrank[i]] = (unsigned short)i;
    __syncthreads();

    // register sums: wave w handles voxels w*16 + pass*8 + (lane>>3); lane q=lane&7 owns uint4 col q
    const int w    = tid >> 6;
    const int lane = tid & 63;
    const int q    = lane & 7;
    const int vsub = lane >> 3;
    const int ybase = p0 - pg;
    const float2* sc2 = (const float2*)sbp;
    const float2* sh2 = (const float2*)(sbp + 64);

    #pragma unroll
    for (int pass = 0; pass < 2; ++pass) {
        int v = w * 16 + pass * 8 + vsub;         // 0..63
        int c0 = cstart[v], c1 = cstart[v + 1];
        float sum[8] = {0,0,0,0,0,0,0,0};
        for (int j = c0; j < c1; ++j) {
            int row = ybase + (int)ridx[j];
            uint4 u = ((const uint4*)Y)[(size_t)row * 8 + q];
            const unsigned* up = (const unsigned*)&u;
            #pragma unroll
            for (int t = 0; t < 4; ++t) {
                sum[2 * t]     += bf2f(up[t] & 0xFFFFu);
                sum[2 * t + 1] += bf2f(up[t] >> 16);
            }
        }
        int og = tile * TILE + v;
        if (LAYER == 0) {
            unsigned o4[4];
            #pragma unroll
            for (int t = 0; t < 4; ++t) {
                int p = q * 4 + t;
                float a = sum[2 * t]     * sc2[p].x + sh2[p].x;
                float b = sum[2 * t + 1] * sc2[p].y + sh2[p].y;
                a = a > 0.f ? a : 0.f; b = b > 0.f ? b : 0.f;
                o4[t] = (unsigned)f2bf(a) | ((unsigned)f2bf(b) << 16);
            }
            ((uint4*)outp)[(size_t)og * 8 + q] = make_uint4(o4[0], o4[1], o4[2], o4[3]);
        } else {
            float* out = (float*)outp;
            #pragma unroll
            for (int t = 0; t < 4; ++t) {
                int p = q * 4 + t;
                int ch0 = (p & 3) * 16 + (p >> 2) * 2;
                float2 xr = *(const float2*)(xres + (size_t)og * 64 + ch0);
                float a = sum[2 * t]     * sc2[p].x + sh2[p].x + xr.x;
                float b = sum[2 * t + 1] * sc2[p].y + sh2[p].y + xr.y;
                a = a > 0.f ? a : 0.f; b = b > 0.f ? b : 0.f;
                *(float2*)(out + (size_t)og * 64 + ch0) = make_float2(a, b);
            }
        }
    }
}

// ---------------- launch ----------------
extern "C" void kernel_launch(void* const* d_in, const int* in_sizes, int n_in,
                              void* d_out, int out_size, void* d_ws, size_t ws_size,
                              hipStream_t stream)
{
    const float* x  = (const float*)d_in[0];
    const float* w1 = (const float*)d_in[1];
    const float* w2 = (const float*)d_in[2];
    const float* g1 = (const float*)d_in[3];
    const float* b1 = (const float*)d_in[4];
    const float* m1 = (const float*)d_in[5];
    const float* v1 = (const float*)d_in[6];
    const float* g2 = (const float*)d_in[7];
    const float* b2 = (const float*)d_in[8];
    const float* m2 = (const float*)d_in[9];
    const float* v2 = (const float*)d_in[10];
    const int* in_map  = (const int*)d_in[11];
    const int* out_map = (const int*)d_in[12];

    char* ws = (char*)d_ws;
    size_t off = 0;
    auto alloc = [&](size_t bytes) -> void* {
        void* p = ws + off;
        off = (off + bytes + 255) & ~(size_t)255;
        return p;
    };
    int* partial   = (int*)alloc((size_t)KB * PTS * 4);          // 5.5 MB
    int* partial_T = (int*)alloc((size_t)NT * KB * 4);           // 5.4 MB
    int* base      = (int*)alloc((size_t)KB * PTS * 4);          // 5.5 MB (slice-major base table)
    int* offs      = (int*)alloc((size_t)(NB + 1) * 4);
    int* cdoffs    = (int*)alloc((size_t)(NB + 1) * 4);
    int* part      = (int*)alloc(512 * 4);
    float* sbp1    = (float*)alloc(128 * 4);
    float* sbp2    = (float*)alloc(128 * 4);
    unsigned short* wb1 = (unsigned short*)alloc((size_t)WBN * 2);
    unsigned short* wb2 = (unsigned short*)alloc((size_t)WBN * 2);
    unsigned* pp   = (unsigned*)alloc((size_t)KM * 4);           // 10.8 MB
    unsigned long long* cdesc = (unsigned long long*)alloc((size_t)CDCAP * 8);
    unsigned short* xb = (unsigned short*)alloc((size_t)N_VOX * C_CH * 2);  // 25.6 MB
    unsigned short* hb = (unsigned short*)alloc((size_t)N_VOX * C_CH * 2);  // 25.6 MB
    size_t baseB = off;

    // group ladder: Y holds one group of bf16 rows (+80 scratch rows); prefer L3-resident sizes
    const int ngs[4]  = {8, 16, 32, 64};
    const int caps[4] = {345000, 175000, 90000, 47000};
    int NG = 64, CAP = 47000;
    for (int i = 0; i < 4; ++i) {
        size_t need = baseB + ((size_t)caps[i] + 80) * 128;
        if (ws_size >= need) { NG = ngs[i]; CAP = caps[i]; break; }
    }
    unsigned* Y = (unsigned*)alloc(((size_t)CAP + 80) * 128);
    const int TPG = (NT + NG - 1) / NG;

    const long TOT = (long)N_VOX * C_CH / 8 + 2 * WBN + 128;
    prep_kernel<<<(int)((TOT + 255) / 256), 256, 0, stream>>>(
        x, w1, w2, g1, b1, m1, v1, g2, b2, m2, v2,
        xb, wb1, wb2, sbp1, sbp2);

    hist_kernel<<<KB, 256, 0, stream>>>(out_map, partial);
    transp_kernel<<<14 * ((NT + 31) / 32), 256, 0, stream>>>(partial, partial_T);
    scanA_kernel<<<NBLK1, 256, 0, stream>>>(partial_T, part);
    scanB_kernel<<<2, 128, 0, stream>>>(part);
    scanC_kernel<<<NBLK1, 256, 0, stream>>>(partial_T, part, offs, cdoffs, base);
    scatter2_kernel<<<KB, 256, 0, stream>>>(in_map, out_map, base, pp);
    cdescb_kernel<<<(NB + 255) / 256, 256, 0, stream>>>(offs, cdoffs, cdesc);

    const int capC = CAP / 16 + TPG * K_OFF + 8;
    const int cyb = (capC + 3) / 4;

    for (int L = 0; L < 2; ++L) {
        const unsigned short* src = (L == 0) ? xb : hb;
        const unsigned short* wbL = (L == 0) ? wb1 : wb2;
        for (int g = 0; g < NG; ++g) {
            int tg0 = g * TPG;
            int tg1 = tg0 + TPG; if (tg1 > NT) tg1 = NT;
            if (tg0 >= tg1) break;
            computeY_kernel<<<cyb, 256, 0, stream>>>(
                src, wbL, pp, cdesc,
                cdoffs + (size_t)tg0 * K_OFF, cdoffs + (size_t)tg1 * K_OFF,
                offs + (size_t)tg0 * K_OFF, Y, CAP);
            if (L == 0)
                reduce_kernel<0><<<tg1 - tg0, 256, 0, stream>>>(
                    Y, pp, offs, offs + (size_t)tg0 * K_OFF, sbp1, nullptr, hb, tg0, CAP);
            else
                reduce_kernel<1><<<tg1 - tg0, 256, 0, stream>>>(
                    Y, pp, offs, offs + (size_t)tg0 * K_OFF, sbp2, x, d_out, tg0, CAP);
        }
    }
}

// Round 13
// 614.273 us; speedup vs baseline: 1.2799x; 1.2799x over previous
//
#include <hip/hip_runtime.h>
#include <stdint.h>

// Problem constants
#define N_VOX    200000
#define C_CH     64
#define K_OFF    27
#define M_PAIRS  100000
#define KM       (K_OFF * M_PAIRS)          // 2,700,000 pairs
#define TILE     64                         // output voxels per tile (o>>6)
#define NT       (N_VOX / TILE)             // 3125 tiles exactly
#define NB       (NT * K_OFF)               // 84375 (tile,k) buckets
#define WBN      (K_OFF * 4096)             // 110592 weight elems per layer
#define EPS_BN   1e-5f
#define CDCAP    (KM / 16 + NB + 64)        // max total chunks

// slice decomposition (atomic-free sort)
#define SLICES   16
#define SLICE_LEN (M_PAIRS / SLICES)        // 6250
#define KB       (K_OFF * SLICES)           // 432
#define PTS      3200                       // plane stride (3125 padded)

// hierarchical scan geometry
#define SCHUNK   2048
#define NBLK1    ((NB + SCHUNK - 1) / SCHUNK)   // 42
#define PQ1      0
#define PQ2      128

// reduce capacity (rows per tile; mean 864, sigma ~29 -> 1536 is ~23 sigma)
#define RCAP     1536

typedef __attribute__((ext_vector_type(8))) short   short8_t;  // 8 x bf16
typedef __attribute__((ext_vector_type(4))) float   f32x4;

__device__ __forceinline__ unsigned short f2bf(float f) {
    union { float f; unsigned u; } v; v.f = f;
    unsigned r = v.u + 0x7FFFu + ((v.u >> 16) & 1u);   // RTNE
    return (unsigned short)(r >> 16);
}
__device__ __forceinline__ float bf2f(unsigned u16) {
    union { unsigned u; float f; } v; v.u = u16 << 16;
    return v.f;
}
// position-layout channel index -> standard channel
__device__ __forceinline__ int pmap(int cs) {
    int p = cs >> 1, h = cs & 1;
    return (p & 3) * 16 + (p >> 2) * 2 + h;
}

// ---------- prep: xb convert (8-wide), w1 (std) / w2 (PMAP-Cin) B-frag swizzle, BN fold ----------
__global__ void prep_kernel(const float* __restrict__ x,
                            const float* __restrict__ w1, const float* __restrict__ w2,
                            const float* __restrict__ g1, const float* __restrict__ b1,
                            const float* __restrict__ m1, const float* __restrict__ v1,
                            const float* __restrict__ g2, const float* __restrict__ b2,
                            const float* __restrict__ m2, const float* __restrict__ v2,
                            unsigned short* __restrict__ xb,
                            unsigned short* __restrict__ wb1, unsigned short* __restrict__ wb2,
                            float* __restrict__ sbp1, float* __restrict__ sbp2)
{
    long i = (long)blockIdx.x * blockDim.x + threadIdx.x;
    const long XBN8 = (long)N_VOX * C_CH / 8;   // 1.6M
    if (i < XBN8) {
        const f32x4* sp = (const f32x4*)(x + (size_t)i * 8);
        f32x4 a = sp[0], b = sp[1];
        uint4 o;
        o.x = (unsigned)f2bf(a[0]) | ((unsigned)f2bf(a[1]) << 16);
        o.y = (unsigned)f2bf(a[2]) | ((unsigned)f2bf(a[3]) << 16);
        o.z = (unsigned)f2bf(b[0]) | ((unsigned)f2bf(b[1]) << 16);
        o.w = (unsigned)f2bf(b[2]) | ((unsigned)f2bf(b[3]) << 16);
        ((uint4*)xb)[i] = o;
        return;
    }
    long j = i - XBN8;
    if (j < 2 * WBN) {
        int isw2 = j >= WBN;
        int o = (int)(isw2 ? j - WBN : j);
        int k   = o >> 12;
        int rem = o & 4095;
        int t  = rem >> 11;
        int sl = (rem >> 9) & 3;
        int d  = (rem >> 3) & 63;
        int jj = rem & 7;
        int cs = t * 32 + sl * 8 + jj;      // A k-slot
        if (!isw2) wb1[o] = f2bf(w1[k * 4096 + cs * 64 + d]);
        else       wb2[o] = f2bf(w2[k * 4096 + pmap(cs) * 64 + d]);  // hb is position-permuted
        return;
    }
    j -= 2 * WBN;
    if (j < 128) {
        int L = (int)(j >= 64);
        int ch = (int)(j & 63);
        float gv = L ? g2[ch] : g1[ch];
        float vv = L ? v2[ch] : v1[ch];
        float mv = L ? m2[ch] : m1[ch];
        float bv = L ? b2[ch] : b1[ch];
        float s = gv * rsqrtf(vv + EPS_BN);
        float sh = bv - mv * s;
        int n = ch >> 4, rem = ch & 15, m = rem >> 1, h = rem & 1;
        int idx = 2 * (m * 4 + n) + h;      // position-layout slot
        float* sbp = L ? sbp2 : sbp1;
        sbp[idx] = s; sbp[64 + idx] = sh;
    }
}

// ---------- hist: per-(k,slice) block, LDS tile-histogram, coalesced partial write ----------
__global__ __launch_bounds__(256) void hist_kernel(const int* __restrict__ out_map,
                                                   int* __restrict__ partial)
{
    __shared__ int h[3136];
    int blk = blockIdx.x;                 // 432 = 27k x 16s
    int k = blk >> 4, s = blk & 15;
    int tid = threadIdx.x;
    for (int i = tid; i < 3136; i += 256) h[i] = 0;
    __syncthreads();
    int p0 = k * M_PAIRS + s * SLICE_LEN;
    for (int i = tid; i < SLICE_LEN; i += 256)
        atomicAdd(&h[out_map[p0 + i] >> 6], 1);
    __syncthreads();
    for (int t = tid; t < NT; t += 256)
        partial[blk * PTS + t] = h[t];
}

// ---------- transpose partial[kb][t] -> partial_T[t][kb] (LDS-tiled) ----------
__global__ __launch_bounds__(256) void transp_kernel(const int* __restrict__ partial,
                                                     int* __restrict__ partial_T)
{
    __shared__ int tb[32][33];
    int bx = blockIdx.x % 14, by = blockIdx.x / 14;
    int kb0 = bx * 32, t0 = by * 32;
    int tx = threadIdx.x & 31, ty = threadIdx.x >> 5;   // ty 0..7
    #pragma unroll
    for (int dy = 0; dy < 32; dy += 8) {
        int kb = kb0 + ty + dy;
        tb[ty + dy][tx] = (kb < KB) ? partial[kb * PTS + t0 + tx] : 0;
    }
    __syncthreads();
    #pragma unroll
    for (int dy = 0; dy < 32; dy += 8) {
        int t = t0 + ty + dy;
        int kb = kb0 + tx;
        if (t < NT && kb < KB)
            partial_T[t * KB + kb] = tb[tx][ty + dy];
    }
}

// ---------- scanA: per-2048-bucket partial sums (raw + ceil16) ----------
__global__ __launch_bounds__(256) void scanA_kernel(const int* __restrict__ partial_T,
                                                    int* __restrict__ part)
{
    __shared__ int lds[256], lds2[256];
    int b0 = blockIdx.x * SCHUNK;
    int t = threadIdx.x;
    int sraw = 0, sc16 = 0;
    for (int i = t; i < SCHUNK; i += 256) {
        int b = b0 + i;
        if (b < NB) {
            int tt = b / K_OFF, k = b % K_OFF;
            const int* pr = &partial_T[tt * KB + k * SLICES];
            int c = 0;
            #pragma unroll
            for (int s = 0; s < SLICES; ++s) c += pr[s];
            sraw += c; sc16 += (c + 15) >> 4;
        }
    }
    lds[t] = sraw; lds2[t] = sc16;
    __syncthreads();
    for (int d = 128; d > 0; d >>= 1) {
        if (t < d) { lds[t] += lds[t + d]; lds2[t] += lds2[t + d]; }
        __syncthreads();
    }
    if (t == 0) { part[PQ1 + blockIdx.x] = lds[0]; part[PQ2 + blockIdx.x] = lds2[0]; }
}

// ---------- scanB: exclusive scan of chunk partials (2 segments) ----------
__global__ __launch_bounds__(128) void scanB_kernel(int* __restrict__ part) {
    __shared__ int lds[128];
    int g = blockIdx.x, t = threadIdx.x;
    int base = (g == 0) ? PQ1 : PQ2;
    int v = (t < NBLK1) ? part[base + t] : 0;
    lds[t] = v;
    __syncthreads();
    for (int d = 1; d < 128; d <<= 1) {
        int u = (t >= d) ? lds[t - d] : 0;
        __syncthreads();
        lds[t] += u;
        __syncthreads();
    }
    if (t < NBLK1) part[base + t] = lds[t] - v;
}

// ---------- scanC: chunk-local scan + base -> offs/cdoffs; fused slice-major base table ----------
__global__ __launch_bounds__(256) void scanC_kernel(const int* __restrict__ partial_T,
                                                    const int* __restrict__ part,
                                                    int* __restrict__ offs,
                                                    int* __restrict__ cdoffs,
                                                    int* __restrict__ base)   // [(k*16+s)][t] (stride PTS)
{
    __shared__ int lds[256], lds2[256];
    int b = blockIdx.x, t = threadIdx.x;
    int i0 = b * SCHUNK + t * 8;
    int c[8]; int sraw = 0, sc16 = 0;
    #pragma unroll
    for (int j = 0; j < 8; ++j) {
        int idx = i0 + j;
        int tot = 0;
        if (idx < NB) {
            int tt = idx / K_OFF, k = idx - tt * K_OFF;
            const int* pr = &partial_T[tt * KB + k * SLICES];
            #pragma unroll
            for (int s = 0; s < SLICES; ++s) tot += pr[s];
        }
        c[j] = tot;
        sraw += tot; sc16 += (tot + 15) >> 4;
    }
    int vr = sraw, vc = sc16;
    lds[t] = vr; lds2[t] = vc;
    __syncthreads();
    for (int d = 1; d < 256; d <<= 1) {
        int ur = (t >= d) ? lds[t - d] : 0;
        int uc = (t >= d) ? lds2[t - d] : 0;
        __syncthreads();
        lds[t] += ur; lds2[t] += uc;
        __syncthreads();
    }
    int braw = part[PQ1 + b] + lds[t] - vr;
    int bc16 = part[PQ2 + b] + lds2[t] - vc;
    #pragma unroll
    for (int j = 0; j < 8; ++j) {
        int idx = i0 + j;
        if (idx < NB) {
            offs[idx] = braw; cdoffs[idx] = bc16;
            int tt = idx / K_OFF, k = idx - tt * K_OFF;
            const int* pr = &partial_T[tt * KB + k * SLICES];
            int run = braw;
            #pragma unroll
            for (int s = 0; s < SLICES; ++s) {
                base[(k * SLICES + s) * PTS + tt] = run;
                run += pr[s];
            }
        }
        braw += c[j]; bc16 += (c[j] + 15) >> 4;
    }
    if (b == NBLK1 - 1 && t == 255) { offs[NB] = braw; cdoffs[NB] = bc16; }
}

// ---------- scatter2 v2: LDS-staged base row, zero global random reads ----------
__global__ __launch_bounds__(256) void scatter2_kernel(const int* __restrict__ in_map,
                                                       const int* __restrict__ out_map,
                                                       const int* __restrict__ base,
                                                       unsigned* __restrict__ pp)
{
    __shared__ int lbase[NT];                 // 12.5 KB
    __shared__ int h2[NT];                    // 12.5 KB rank counters
    int blk = blockIdx.x;
    int k = blk >> 4, s = blk & 15;
    int tid = threadIdx.x;
    const int* gb = &base[(k * SLICES + s) * PTS];
    for (int i = tid; i < NT; i += 256) { lbase[i] = gb[i]; h2[i] = 0; }
    __syncthreads();
    int p0 = k * M_PAIRS + s * SLICE_LEN;
    #pragma unroll 2
    for (int i = tid; i < SLICE_LEN; i += 256) {
        int p = p0 + i;
        int o = out_map[p];
        int t = o >> 6;
        int rank = atomicAdd(&h2[t], 1);      // LDS-only atomic
        pp[lbase[t] + rank] = (unsigned)in_map[p] | ((unsigned)(o & 63) << 18);
    }
}

// ---------- build global chunk descriptors: k | pbase<<5 | pend<<27 ----------
__global__ void cdescb_kernel(const int* __restrict__ offs, const int* __restrict__ cdoffs,
                              unsigned long long* __restrict__ cdesc)
{
    int b = blockIdx.x * 256 + threadIdx.x;
    if (b >= NB) return;
    int k = b % K_OFF;
    int c0 = cdoffs[b];
    int nchunk = cdoffs[b + 1] - c0;
    int base = offs[b];
    int end  = offs[b + 1];
    for (int i = 0; i < nchunk; ++i)
        cdesc[c0 + i] = (unsigned long long)k
                      | ((unsigned long long)(base + 16 * i) << 5)
                      | ((unsigned long long)end << 27);
}

// ---------- computeY: one chunk per wave; gather 16 bf16 rows, 8 MFMA, repack, seq Y write ----------
__global__ __launch_bounds__(256) void computeY_kernel(
    const unsigned short* __restrict__ xin,     // bf16 rows [N][64] (xb std / hb position-layout)
    const unsigned short* __restrict__ wb,      // pre-swizzled bf16 weights
    const unsigned* __restrict__ pp,            // iidx | oloc<<18, (tile,k)-sorted
    const unsigned long long* __restrict__ cdesc,
    const int* __restrict__ csp,                // &cdoffs[tg0*27]
    const int* __restrict__ cep,                // &cdoffs[tg1*27]
    const int* __restrict__ pgb,                // &offs[tg0*27] (group pos base)
    unsigned* __restrict__ Y,                   // rows of 32 u32 (bf16 pairs, position layout)
    int ycap)
{
    int c = csp[0] + blockIdx.x * 4 + (threadIdx.x >> 6);
    if (c >= cep[0]) return;
    unsigned long long d = cdesc[c];
    int k     = (int)(d & 31);
    int pbase = (int)((d >> 5) & 0x3FFFFF);
    int pend  = (int)(d >> 27);
    int pg = pgb[0];
    int lane  = threadIdx.x & 63;
    int r     = lane & 15;
    int sfour = lane >> 4;
    int par   = lane & 1;

    int ii = pbase + r;
    bool real = ii < pend;
    unsigned pv = pp[real ? ii : pbase];
    unsigned iidx = pv & 0x3FFFFu;
    int yr;
    if (real) { yr = ii - pg; if (yr > ycap) yr = ycap; }
    else      { yr = ycap + 8 + (c & 63); }

    const short8_t* xrow = (const short8_t*)(xin + (size_t)iidx * 64);
    short8_t A0 = xrow[sfour];
    short8_t A1 = xrow[4 + sfour];
    const short8_t* wbk = (const short8_t*)(wb + k * 4096);

    f32x4 acc[4] = {{0,0,0,0},{0,0,0,0},{0,0,0,0},{0,0,0,0}};
    #pragma unroll
    for (int n = 0; n < 4; ++n) {
        acc[n] = __builtin_amdgcn_mfma_f32_16x16x32_bf16(A0, wbk[sfour * 64 + n * 16 + r], acc[n], 0, 0, 0);
        acc[n] = __builtin_amdgcn_mfma_f32_16x16x32_bf16(A1, wbk[(4 + sfour) * 64 + n * 16 + r], acc[n], 0, 0, 0);
    }

    // repack D (col=n*16+r, row=sfour*4+j) into bf16 Y rows; lane-pair exchange packs ch pairs
    #pragma unroll
    for (int jj = 0; jj < 4; jj += 2) {
        uint4 w;
        unsigned* wp = (unsigned*)&w;
        #pragma unroll
        for (int n = 0; n < 4; ++n) {
            float mine = par ? acc[n][jj + 1] : acc[n][jj];
            float send = par ? acc[n][jj]     : acc[n][jj + 1];
            float tt = __shfl_xor(send, 1, 64);
            float lo = par ? tt : mine;
            float hi = par ? mine : tt;
            wp[n] = (unsigned)f2bf(lo) | ((unsigned)f2bf(hi) << 16);
        }
        int Rw = sfour * 4 + jj + par;
        int yrow = __shfl(yr, Rw, 64);
        ((uint4*)Y)[(size_t)yrow * 8 + (r >> 1)] = w;
    }
}

// ---------- reduce v2: LDS rank/permute (int atomics only), register-sum per voxel ----------
template<int LAYER>
__global__ __launch_bounds__(256) void reduce_kernel(
    const unsigned* __restrict__ Y,
    const unsigned* __restrict__ pp,
    const int* __restrict__ offs,
    const int* __restrict__ pgb,
    const float* __restrict__ sbp,              // [0:64) scale, [64:128) shift (position order)
    const float* __restrict__ xres,             // LAYER==1 residual (std layout)
    void* __restrict__ outp,                    // L0: hb (bf16 position layout); L1: f32 std
    int tg0, int ycap)
{
    __shared__ unsigned short ridx[RCAP];
    __shared__ unsigned short rrank[RCAP];
    __shared__ unsigned char  soloc[RCAP];
    __shared__ int hist[TILE];
    __shared__ int cstart[TILE + 1];

    const int tile = tg0 + blockIdx.x;
    const int tid = threadIdx.x;
    const int p0 = offs[tile * K_OFF];
    const int p1 = offs[(tile + 1) * K_OFF];
    const int pg = pgb[0];
    int nr = p1 - p0; if (nr > RCAP) nr = RCAP;

    if (tid < TILE) hist[tid] = 0;
    __syncthreads();
    for (int i = tid; i < nr; i += 256) {
        int ol = (int)((pp[p0 + i] >> 18) & 63);
        soloc[i] = (unsigned char)ol;
        rrank[i] = (unsigned short)atomicAdd(&hist[ol], 1);   // LDS int atomic, 64 bins
    }
    __syncthreads();
    if (tid < 64) {                               // exclusive prefix of 64 bins (wave 0)
        int v = hist[tid];
        int s = v;
        #pragma unroll
        for (int d = 1; d < 64; d <<= 1) {
            int u = __shfl_up(s, d, 64);
            if (tid >= d) s += u;
        }
        cstart[tid] = s - v;
        if (tid == 63) cstart[64] = s;
    }
    __syncthreads();
    for (int i = tid; i < nr; i += 256)
        ridx[cstart[soloc[i]] + rrank[i]] = (unsigned short)i;
    __syncthreads();

    // register sums: wave w handles voxels w*16 + pass*8 + (lane>>3); lane q=lane&7 owns uint4 col q
    const int w    = tid >> 6;
    const int lane = tid & 63;
    const int q    = lane & 7;
    const int vsub = lane >> 3;
    const int ybase = p0 - pg;
    const float2* sc2 = (const float2*)sbp;
    const float2* sh2 = (const float2*)(sbp + 64);

    #pragma unroll
    for (int pass = 0; pass < 2; ++pass) {
        int v = w * 16 + pass * 8 + vsub;         // 0..63
        int c0 = cstart[v], c1 = cstart[v + 1];
        float sum[8] = {0,0,0,0,0,0,0,0};
        for (int j = c0; j < c1; ++j) {
            int row = ybase + (int)ridx[j];
            uint4 u = ((const uint4*)Y)[(size_t)row * 8 + q];
            const unsigned* up = (const unsigned*)&u;
            #pragma unroll
            for (int t = 0; t < 4; ++t) {
                sum[2 * t]     += bf2f(up[t] & 0xFFFFu);
                sum[2 * t + 1] += bf2f(up[t] >> 16);
            }
        }
        int og = tile * TILE + v;
        if (LAYER == 0) {
            unsigned o4[4];
            #pragma unroll
            for (int t = 0; t < 4; ++t) {
                int p = q * 4 + t;
                float a = sum[2 * t]     * sc2[p].x + sh2[p].x;
                float b = sum[2 * t + 1] * sc2[p].y + sh2[p].y;
                a = a > 0.f ? a : 0.f; b = b > 0.f ? b : 0.f;
                o4[t] = (unsigned)f2bf(a) | ((unsigned)f2bf(b) << 16);
            }
            ((uint4*)outp)[(size_t)og * 8 + q] = make_uint4(o4[0], o4[1], o4[2], o4[3]);
        } else {
            float* out = (float*)outp;
            #pragma unroll
            for (int t = 0; t < 4; ++t) {
                int p = q * 4 + t;
                int ch0 = (p & 3) * 16 + (p >> 2) * 2;
                float2 xr = *(const float2*)(xres + (size_t)og * 64 + ch0);
                float a = sum[2 * t]     * sc2[p].x + sh2[p].x + xr.x;
                float b = sum[2 * t + 1] * sc2[p].y + sh2[p].y + xr.y;
                a = a > 0.f ? a : 0.f; b = b > 0.f ? b : 0.f;
                *(float2*)(out + (size_t)og * 64 + ch0) = make_float2(a, b);
            }
        }
    }
}

// ---------------- launch ----------------
extern "C" void kernel_launch(void* const* d_in, const int* in_sizes, int n_in,
                              void* d_out, int out_size, void* d_ws, size_t ws_size,
                              hipStream_t stream)
{
    const float* x  = (const float*)d_in[0];
    const float* w1 = (const float*)d_in[1];
    const float* w2 = (const float*)d_in[2];
    const float* g1 = (const float*)d_in[3];
    const float* b1 = (const float*)d_in[4];
    const float* m1 = (const float*)d_in[5];
    const float* v1 = (const float*)d_in[6];
    const float* g2 = (const float*)d_in[7];
    const float* b2 = (const float*)d_in[8];
    const float* m2 = (const float*)d_in[9];
    const float* v2 = (const float*)d_in[10];
    const int* in_map  = (const int*)d_in[11];
    const int* out_map = (const int*)d_in[12];

    char* ws = (char*)d_ws;
    size_t off = 0;
    auto alloc = [&](size_t bytes) -> void* {
        void* p = ws + off;
        off = (off + bytes + 255) & ~(size_t)255;
        return p;
    };
    int* partial   = (int*)alloc((size_t)KB * PTS * 4);          // 5.5 MB
    int* partial_T = (int*)alloc((size_t)NT * KB * 4);           // 5.4 MB
    int* base      = (int*)alloc((size_t)KB * PTS * 4);          // 5.5 MB (slice-major base table)
    int* offs      = (int*)alloc((size_t)(NB + 1) * 4);
    int* cdoffs    = (int*)alloc((size_t)(NB + 1) * 4);
    int* part      = (int*)alloc(512 * 4);
    float* sbp1    = (float*)alloc(128 * 4);
    float* sbp2    = (float*)alloc(128 * 4);
    unsigned short* wb1 = (unsigned short*)alloc((size_t)WBN * 2);
    unsigned short* wb2 = (unsigned short*)alloc((size_t)WBN * 2);
    unsigned* pp   = (unsigned*)alloc((size_t)KM * 4);           // 10.8 MB
    unsigned long long* cdesc = (unsigned long long*)alloc((size_t)CDCAP * 8);
    unsigned short* xb = (unsigned short*)alloc((size_t)N_VOX * C_CH * 2);  // 25.6 MB
    unsigned short* hb = (unsigned short*)alloc((size_t)N_VOX * C_CH * 2);  // 25.6 MB
    size_t baseB = off;

    // group ladder: prefer fewest groups that fit (launch overhead dominates small groups)
    const int ngs[5]  = {4, 8, 16, 32, 64};
    const int caps[5] = {690000, 345000, 175000, 90000, 47000};
    int NG = 64, CAP = 47000;
    for (int i = 0; i < 5; ++i) {
        size_t need = baseB + ((size_t)caps[i] + 80) * 128;
        if (ws_size >= need) { NG = ngs[i]; CAP = caps[i]; break; }
    }
    unsigned* Y = (unsigned*)alloc(((size_t)CAP + 80) * 128);
    const int TPG = (NT + NG - 1) / NG;

    const long TOT = (long)N_VOX * C_CH / 8 + 2 * WBN + 128;
    prep_kernel<<<(int)((TOT + 255) / 256), 256, 0, stream>>>(
        x, w1, w2, g1, b1, m1, v1, g2, b2, m2, v2,
        xb, wb1, wb2, sbp1, sbp2);

    hist_kernel<<<KB, 256, 0, stream>>>(out_map, partial);
    transp_kernel<<<14 * ((NT + 31) / 32), 256, 0, stream>>>(partial, partial_T);
    scanA_kernel<<<NBLK1, 256, 0, stream>>>(partial_T, part);
    scanB_kernel<<<2, 128, 0, stream>>>(part);
    scanC_kernel<<<NBLK1, 256, 0, stream>>>(partial_T, part, offs, cdoffs, base);
    scatter2_kernel<<<KB, 256, 0, stream>>>(in_map, out_map, base, pp);
    cdescb_kernel<<<(NB + 255) / 256, 256, 0, stream>>>(offs, cdoffs, cdesc);

    const int capC = CAP / 16 + TPG * K_OFF + 8;
    const int cyb = (capC + 3) / 4;

    for (int L = 0; L < 2; ++L) {
        const unsigned short* src = (L == 0) ? xb : hb;
        const unsigned short* wbL = (L == 0) ? wb1 : wb2;
        for (int g = 0; g < NG; ++g) {
            int tg0 = g * TPG;
            int tg1 = tg0 + TPG; if (tg1 > NT) tg1 = NT;
            if (tg0 >= tg1) break;
            computeY_kernel<<<cyb, 256, 0, stream>>>(
                src, wbL, pp, cdesc,
                cdoffs + (size_t)tg0 * K_OFF, cdoffs + (size_t)tg1 * K_OFF,
                offs + (size_t)tg0 * K_OFF, Y, CAP);
            if (L == 0)
                reduce_kernel<0><<<tg1 - tg0, 256, 0, stream>>>(
                    Y, pp, offs, offs + (size_t)tg0 * K_OFF, sbp1, nullptr, hb, tg0, CAP);
            else
                reduce_kernel<1><<<tg1 - tg0, 256, 0, stream>>>(
                    Y, pp, offs, offs + (size_t)tg0 * K_OFF, sbp2, x, d_out, tg0, CAP);
        }
    }
}

// Round 14
// 467.891 us; speedup vs baseline: 1.6803x; 1.3129x over previous
//
#include <hip/hip_runtime.h>
#include <stdint.h>

// Problem constants
#define N_VOX    200000
#define C_CH     64
#define K_OFF    27
#define M_PAIRS  100000
#define KM       (K_OFF * M_PAIRS)          // 2,700,000 pairs
#define TILE     64                         // output voxels per tile (o>>6)
#define NT       (N_VOX / TILE)             // 3125 tiles exactly
#define NB       (NT * K_OFF)               // 84375 (tile,k) buckets
#define WBN      (K_OFF * 4096)             // 110592 weight elems per layer
#define EPS_BN   1e-5f
#define CDCAP    (KM / 16 + NB + 64)        // max total chunks

// slice decomposition (atomic-free sort)
#define SLICES   16
#define SLICE_LEN (M_PAIRS / SLICES)        // 6250
#define KB       (K_OFF * SLICES)           // 432
#define PTS      3200                       // plane stride (3125 padded)

// hierarchical scan geometry
#define SCHUNK   2048
#define NBLK1    ((NB + SCHUNK - 1) / SCHUNK)   // 42
#define PQ1      0
#define PQ2      128

// fused-kernel LDS Y capacity (rows per tile; mean 864, sigma ~29 -> 1040 is +6 sigma)
#define YCAP     1040

typedef __attribute__((ext_vector_type(8))) short   short8_t;  // 8 x bf16
typedef __attribute__((ext_vector_type(4))) float   f32x4;

__device__ __forceinline__ unsigned short f2bf(float f) {
    union { float f; unsigned u; } v; v.f = f;
    unsigned r = v.u + 0x7FFFu + ((v.u >> 16) & 1u);   // RTNE
    return (unsigned short)(r >> 16);
}
__device__ __forceinline__ float bf2f(unsigned u16) {
    union { unsigned u; float f; } v; v.u = u16 << 16;
    return v.f;
}
// position-layout channel index -> standard channel
__device__ __forceinline__ int pmap(int cs) {
    int p = cs >> 1, h = cs & 1;
    return (p & 3) * 16 + (p >> 2) * 2 + h;
}

// ---------- prep: xb convert (8-wide), w1 (std) / w2 (PMAP-Cin) B-frag swizzle, BN fold ----------
__global__ void prep_kernel(const float* __restrict__ x,
                            const float* __restrict__ w1, const float* __restrict__ w2,
                            const float* __restrict__ g1, const float* __restrict__ b1,
                            const float* __restrict__ m1, const float* __restrict__ v1,
                            const float* __restrict__ g2, const float* __restrict__ b2,
                            const float* __restrict__ m2, const float* __restrict__ v2,
                            unsigned short* __restrict__ xb,
                            unsigned short* __restrict__ wb1, unsigned short* __restrict__ wb2,
                            float* __restrict__ sbp1, float* __restrict__ sbp2)
{
    long i = (long)blockIdx.x * blockDim.x + threadIdx.x;
    const long XBN8 = (long)N_VOX * C_CH / 8;   // 1.6M
    if (i < XBN8) {
        const f32x4* sp = (const f32x4*)(x + (size_t)i * 8);
        f32x4 a = sp[0], b = sp[1];
        uint4 o;
        o.x = (unsigned)f2bf(a[0]) | ((unsigned)f2bf(a[1]) << 16);
        o.y = (unsigned)f2bf(a[2]) | ((unsigned)f2bf(a[3]) << 16);
        o.z = (unsigned)f2bf(b[0]) | ((unsigned)f2bf(b[1]) << 16);
        o.w = (unsigned)f2bf(b[2]) | ((unsigned)f2bf(b[3]) << 16);
        ((uint4*)xb)[i] = o;
        return;
    }
    long j = i - XBN8;
    if (j < 2 * WBN) {
        int isw2 = j >= WBN;
        int o = (int)(isw2 ? j - WBN : j);
        int k   = o >> 12;
        int rem = o & 4095;
        int t  = rem >> 11;
        int sl = (rem >> 9) & 3;
        int d  = (rem >> 3) & 63;
        int jj = rem & 7;
        int cs = t * 32 + sl * 8 + jj;      // A k-slot
        if (!isw2) wb1[o] = f2bf(w1[k * 4096 + cs * 64 + d]);
        else       wb2[o] = f2bf(w2[k * 4096 + pmap(cs) * 64 + d]);  // hb is position-permuted
        return;
    }
    j -= 2 * WBN;
    if (j < 128) {
        int L = (int)(j >= 64);
        int ch = (int)(j & 63);
        float gv = L ? g2[ch] : g1[ch];
        float vv = L ? v2[ch] : v1[ch];
        float mv = L ? m2[ch] : m1[ch];
        float bv = L ? b2[ch] : b1[ch];
        float s = gv * rsqrtf(vv + EPS_BN);
        float sh = bv - mv * s;
        int n = ch >> 4, rem = ch & 15, m = rem >> 1, h = rem & 1;
        int idx = 2 * (m * 4 + n) + h;      // position-layout slot
        float* sbp = L ? sbp2 : sbp1;
        sbp[idx] = s; sbp[64 + idx] = sh;
    }
}

// ---------- hist: per-(k,slice) block, LDS tile-histogram, coalesced partial write ----------
__global__ __launch_bounds__(256) void hist_kernel(const int* __restrict__ out_map,
                                                   int* __restrict__ partial)
{
    __shared__ int h[3136];
    int blk = blockIdx.x;                 // 432 = 27k x 16s
    int k = blk >> 4, s = blk & 15;
    int tid = threadIdx.x;
    for (int i = tid; i < 3136; i += 256) h[i] = 0;
    __syncthreads();
    int p0 = k * M_PAIRS + s * SLICE_LEN;
    for (int i = tid; i < SLICE_LEN; i += 256)
        atomicAdd(&h[out_map[p0 + i] >> 6], 1);
    __syncthreads();
    for (int t = tid; t < NT; t += 256)
        partial[blk * PTS + t] = h[t];
}

// ---------- transpose partial[kb][t] -> partial_T[t][kb] (LDS-tiled) ----------
__global__ __launch_bounds__(256) void transp_kernel(const int* __restrict__ partial,
                                                     int* __restrict__ partial_T)
{
    __shared__ int tb[32][33];
    int bx = blockIdx.x % 14, by = blockIdx.x / 14;
    int kb0 = bx * 32, t0 = by * 32;
    int tx = threadIdx.x & 31, ty = threadIdx.x >> 5;   // ty 0..7
    #pragma unroll
    for (int dy = 0; dy < 32; dy += 8) {
        int kb = kb0 + ty + dy;
        tb[ty + dy][tx] = (kb < KB) ? partial[kb * PTS + t0 + tx] : 0;
    }
    __syncthreads();
    #pragma unroll
    for (int dy = 0; dy < 32; dy += 8) {
        int t = t0 + ty + dy;
        int kb = kb0 + tx;
        if (t < NT && kb < KB)
            partial_T[t * KB + kb] = tb[tx][ty + dy];
    }
}

// ---------- scanA: per-2048-bucket partial sums (raw + ceil16) ----------
__global__ __launch_bounds__(256) void scanA_kernel(const int* __restrict__ partial_T,
                                                    int* __restrict__ part)
{
    __shared__ int lds[256], lds2[256];
    int b0 = blockIdx.x * SCHUNK;
    int t = threadIdx.x;
    int sraw = 0, sc16 = 0;
    for (int i = t; i < SCHUNK; i += 256) {
        int b = b0 + i;
        if (b < NB) {
            int tt = b / K_OFF, k = b % K_OFF;
            const int* pr = &partial_T[tt * KB + k * SLICES];
            int c = 0;
            #pragma unroll
            for (int s = 0; s < SLICES; ++s) c += pr[s];
            sraw += c; sc16 += (c + 15) >> 4;
        }
    }
    lds[t] = sraw; lds2[t] = sc16;
    __syncthreads();
    for (int d = 128; d > 0; d >>= 1) {
        if (t < d) { lds[t] += lds[t + d]; lds2[t] += lds2[t + d]; }
        __syncthreads();
    }
    if (t == 0) { part[PQ1 + blockIdx.x] = lds[0]; part[PQ2 + blockIdx.x] = lds2[0]; }
}

// ---------- scanB: exclusive scan of chunk partials (2 segments) ----------
__global__ __launch_bounds__(128) void scanB_kernel(int* __restrict__ part) {
    __shared__ int lds[128];
    int g = blockIdx.x, t = threadIdx.x;
    int base = (g == 0) ? PQ1 : PQ2;
    int v = (t < NBLK1) ? part[base + t] : 0;
    lds[t] = v;
    __syncthreads();
    for (int d = 1; d < 128; d <<= 1) {
        int u = (t >= d) ? lds[t - d] : 0;
        __syncthreads();
        lds[t] += u;
        __syncthreads();
    }
    if (t < NBLK1) part[base + t] = lds[t] - v;
}

// ---------- scanC: chunk-local scan + base -> offs/cdoffs; fused slice-major base table ----------
__global__ __launch_bounds__(256) void scanC_kernel(const int* __restrict__ partial_T,
                                                    const int* __restrict__ part,
                                                    int* __restrict__ offs,
                                                    int* __restrict__ cdoffs,
                                                    int* __restrict__ base)   // [(k*16+s)][t] (stride PTS)
{
    __shared__ int lds[256], lds2[256];
    int b = blockIdx.x, t = threadIdx.x;
    int i0 = b * SCHUNK + t * 8;
    int c[8]; int sraw = 0, sc16 = 0;
    #pragma unroll
    for (int j = 0; j < 8; ++j) {
        int idx = i0 + j;
        int tot = 0;
        if (idx < NB) {
            int tt = idx / K_OFF, k = idx - tt * K_OFF;
            const int* pr = &partial_T[tt * KB + k * SLICES];
            #pragma unroll
            for (int s = 0; s < SLICES; ++s) tot += pr[s];
        }
        c[j] = tot;
        sraw += tot; sc16 += (tot + 15) >> 4;
    }
    int vr = sraw, vc = sc16;
    lds[t] = vr; lds2[t] = vc;
    __syncthreads();
    for (int d = 1; d < 256; d <<= 1) {
        int ur = (t >= d) ? lds[t - d] : 0;
        int uc = (t >= d) ? lds2[t - d] : 0;
        __syncthreads();
        lds[t] += ur; lds2[t] += uc;
        __syncthreads();
    }
    int braw = part[PQ1 + b] + lds[t] - vr;
    int bc16 = part[PQ2 + b] + lds2[t] - vc;
    #pragma unroll
    for (int j = 0; j < 8; ++j) {
        int idx = i0 + j;
        if (idx < NB) {
            offs[idx] = braw; cdoffs[idx] = bc16;
            int tt = idx / K_OFF, k = idx - tt * K_OFF;
            const int* pr = &partial_T[tt * KB + k * SLICES];
            int run = braw;
            #pragma unroll
            for (int s = 0; s < SLICES; ++s) {
                base[(k * SLICES + s) * PTS + tt] = run;
                run += pr[s];
            }
        }
        braw += c[j]; bc16 += (c[j] + 15) >> 4;
    }
    if (b == NBLK1 - 1 && t == 255) { offs[NB] = braw; cdoffs[NB] = bc16; }
}

// ---------- scatter2: LDS-staged base row, zero global random reads ----------
__global__ __launch_bounds__(256) void scatter2_kernel(const int* __restrict__ in_map,
                                                       const int* __restrict__ out_map,
                                                       const int* __restrict__ base,
                                                       unsigned* __restrict__ pp)
{
    __shared__ int lbase[NT];                 // 12.5 KB
    __shared__ int h2[NT];                    // 12.5 KB rank counters
    int blk = blockIdx.x;
    int k = blk >> 4, s = blk & 15;
    int tid = threadIdx.x;
    const int* gb = &base[(k * SLICES + s) * PTS];
    for (int i = tid; i < NT; i += 256) { lbase[i] = gb[i]; h2[i] = 0; }
    __syncthreads();
    int p0 = k * M_PAIRS + s * SLICE_LEN;
    #pragma unroll 2
    for (int i = tid; i < SLICE_LEN; i += 256) {
        int p = p0 + i;
        int o = out_map[p];
        int t = o >> 6;
        int rank = atomicAdd(&h2[t], 1);      // LDS-only atomic
        pp[lbase[t] + rank] = (unsigned)in_map[p] | ((unsigned)(o & 63) << 18);
    }
}

// ---------- build global chunk descriptors: k | pbase<<5 | pend<<27 ----------
__global__ void cdescb_kernel(const int* __restrict__ offs, const int* __restrict__ cdoffs,
                              unsigned long long* __restrict__ cdesc)
{
    int b = blockIdx.x * 256 + threadIdx.x;
    if (b >= NB) return;
    int k = b % K_OFF;
    int c0 = cdoffs[b];
    int nchunk = cdoffs[b + 1] - c0;
    int base = offs[b];
    int end  = offs[b + 1];
    for (int i = 0; i < nchunk; ++i)
        cdesc[c0 + i] = (unsigned long long)k
                      | ((unsigned long long)(base + 16 * i) << 5)
                      | ((unsigned long long)end << 27);
}

// ---------- fused conv: per-tile computeY into LDS + rank-permute register reduce + BN epilogue ----------
// 1 block per 64-voxel tile, 1024 threads (16 waves), ~140 KB LDS, 1 block/CU.
template<int LAYER>
__global__ __launch_bounds__(1024, 1) void fused_kernel(
    const unsigned short* __restrict__ xin,     // bf16 rows [N][64] (xb std / hb position-layout)
    const unsigned short* __restrict__ wb,      // pre-swizzled bf16 weights
    const unsigned* __restrict__ pp,            // iidx | oloc<<18, (tile,k)-sorted
    const unsigned long long* __restrict__ cdesc,
    const int* __restrict__ offs,
    const int* __restrict__ cdoffs,
    const float* __restrict__ sbp,              // [0:64) scale, [64:128) shift (position order)
    const float* __restrict__ xres,             // LAYER==1 residual (std layout)
    void* __restrict__ outp)                    // L0: hb (bf16 position layout); L1: f32 std
{
    __shared__ unsigned Ylds[(YCAP + 8) * 32];  // 134.1 KB (8 trash rows for pads/overflow)
    __shared__ unsigned short ridx[YCAP];
    __shared__ unsigned short rrank[YCAP];
    __shared__ unsigned char  soloc[YCAP];
    __shared__ int hist[TILE];
    __shared__ int cstart[TILE + 1];

    const int tile = blockIdx.x;
    const int tid = threadIdx.x;
    const int p0 = offs[tile * K_OFF];
    const int p1 = offs[(tile + 1) * K_OFF];
    const int c0 = cdoffs[tile * K_OFF];
    const int c1 = cdoffs[(tile + 1) * K_OFF];
    int nr = p1 - p0; if (nr > YCAP) nr = YCAP;

    // ---- rank/permute tables (reduce-v2 logic) ----
    if (tid < TILE) hist[tid] = 0;
    __syncthreads();
    for (int i = tid; i < nr; i += 1024) {
        int ol = (int)((pp[p0 + i] >> 18) & 63);
        soloc[i] = (unsigned char)ol;
        rrank[i] = (unsigned short)atomicAdd(&hist[ol], 1);
    }
    __syncthreads();
    if (tid < 64) {
        int v = hist[tid];
        int s = v;
        #pragma unroll
        for (int d = 1; d < 64; d <<= 1) {
            int u = __shfl_up(s, d, 64);
            if (tid >= d) s += u;
        }
        cstart[tid] = s - v;
        if (tid == 63) cstart[64] = s;
    }
    __syncthreads();
    for (int i = tid; i < nr; i += 1024)
        ridx[cstart[soloc[i]] + rrank[i]] = (unsigned short)i;

    // ---- phase 1: one chunk per wave, D-repack into LDS Y rows ----
    const int wid   = tid >> 6;
    const int lane  = tid & 63;
    const int r     = lane & 15;
    const int sfour = lane >> 4;
    const int par   = lane & 1;

    for (int c = c0 + wid; c < c1; c += 16) {
        unsigned long long d = cdesc[c];
        int k     = (int)(d & 31);
        int pbase = (int)((d >> 5) & 0x3FFFFF);
        int pend  = (int)(d >> 27);

        int ii = pbase + r;
        bool real = ii < pend;
        unsigned pv = pp[real ? ii : pbase];
        unsigned iidx = pv & 0x3FFFFu;
        int yr;
        if (real) { yr = ii - p0; if (yr > YCAP) yr = YCAP; }
        else      { yr = YCAP + (c & 7); }

        const short8_t* xrow = (const short8_t*)(xin + (size_t)iidx * 64);
        short8_t A0 = xrow[sfour];
        short8_t A1 = xrow[4 + sfour];
        const short8_t* wbk = (const short8_t*)(wb + k * 4096);

        f32x4 acc[4] = {{0,0,0,0},{0,0,0,0},{0,0,0,0},{0,0,0,0}};
        #pragma unroll
        for (int n = 0; n < 4; ++n) {
            acc[n] = __builtin_amdgcn_mfma_f32_16x16x32_bf16(A0, wbk[sfour * 64 + n * 16 + r], acc[n], 0, 0, 0);
            acc[n] = __builtin_amdgcn_mfma_f32_16x16x32_bf16(A1, wbk[(4 + sfour) * 64 + n * 16 + r], acc[n], 0, 0, 0);
        }

        // repack D (col=n*16+r, row=sfour*4+j) into bf16 Y rows in LDS
        #pragma unroll
        for (int jj = 0; jj < 4; jj += 2) {
            uint4 w;
            unsigned* wp = (unsigned*)&w;
            #pragma unroll
            for (int n = 0; n < 4; ++n) {
                float mine = par ? acc[n][jj + 1] : acc[n][jj];
                float send = par ? acc[n][jj]     : acc[n][jj + 1];
                float tt = __shfl_xor(send, 1, 64);
                float lo = par ? tt : mine;
                float hi = par ? mine : tt;
                wp[n] = (unsigned)f2bf(lo) | ((unsigned)f2bf(hi) << 16);
            }
            int Rw = sfour * 4 + jj + par;
            int yrow = __shfl(yr, Rw, 64);
            *(uint4*)&Ylds[(unsigned)yrow * 32 + (r >> 1) * 4] = w;
        }
    }
    __syncthreads();

    // ---- phase 2: register sums per voxel from LDS + BN(+relu)(+residual) ----
    const int v  = tid >> 4;        // voxel 0..63
    const int q2 = tid & 15;        // u32 pair: positions 2q2, 2q2+1 (4 bf16 channels)
    int cs0 = cstart[v], cs1 = cstart[v + 1];
    float sum[4] = {0.f, 0.f, 0.f, 0.f};
    for (int j = cs0; j < cs1; ++j) {
        int row = (int)ridx[j];
        uint2 u = *(const uint2*)&Ylds[(unsigned)row * 32 + 2 * q2];
        sum[0] += bf2f(u.x & 0xFFFFu);
        sum[1] += bf2f(u.x >> 16);
        sum[2] += bf2f(u.y & 0xFFFFu);
        sum[3] += bf2f(u.y >> 16);
    }

    const int og = tile * TILE + v;
    const float2* sc2 = (const float2*)sbp;
    const float2* sh2 = (const float2*)(sbp + 64);
    int pA = 2 * q2, pB = 2 * q2 + 1;
    float a0 = sum[0] * sc2[pA].x + sh2[pA].x;
    float a1 = sum[1] * sc2[pA].y + sh2[pA].y;
    float b0 = sum[2] * sc2[pB].x + sh2[pB].x;
    float b1 = sum[3] * sc2[pB].y + sh2[pB].y;
    if (LAYER == 0) {
        a0 = a0 > 0.f ? a0 : 0.f; a1 = a1 > 0.f ? a1 : 0.f;
        b0 = b0 > 0.f ? b0 : 0.f; b1 = b1 > 0.f ? b1 : 0.f;
        uint2 o2;
        o2.x = (unsigned)f2bf(a0) | ((unsigned)f2bf(a1) << 16);
        o2.y = (unsigned)f2bf(b0) | ((unsigned)f2bf(b1) << 16);
        *(uint2*)((unsigned*)outp + (size_t)og * 32 + 2 * q2) = o2;
    } else {
        float* out = (float*)outp;
        int chA = (pA & 3) * 16 + (pA >> 2) * 2;
        int chB = (pB & 3) * 16 + (pB >> 2) * 2;
        float2 xrA = *(const float2*)(xres + (size_t)og * 64 + chA);
        float2 xrB = *(const float2*)(xres + (size_t)og * 64 + chB);
        a0 += xrA.x; a1 += xrA.y; b0 += xrB.x; b1 += xrB.y;
        a0 = a0 > 0.f ? a0 : 0.f; a1 = a1 > 0.f ? a1 : 0.f;
        b0 = b0 > 0.f ? b0 : 0.f; b1 = b1 > 0.f ? b1 : 0.f;
        *(float2*)(out + (size_t)og * 64 + chA) = make_float2(a0, a1);
        *(float2*)(out + (size_t)og * 64 + chB) = make_float2(b0, b1);
    }
}

// ---------------- launch ----------------
extern "C" void kernel_launch(void* const* d_in, const int* in_sizes, int n_in,
                              void* d_out, int out_size, void* d_ws, size_t ws_size,
                              hipStream_t stream)
{
    const float* x  = (const float*)d_in[0];
    const float* w1 = (const float*)d_in[1];
    const float* w2 = (const float*)d_in[2];
    const float* g1 = (const float*)d_in[3];
    const float* b1 = (const float*)d_in[4];
    const float* m1 = (const float*)d_in[5];
    const float* v1 = (const float*)d_in[6];
    const float* g2 = (const float*)d_in[7];
    const float* b2 = (const float*)d_in[8];
    const float* m2 = (const float*)d_in[9];
    const float* v2 = (const float*)d_in[10];
    const int* in_map  = (const int*)d_in[11];
    const int* out_map = (const int*)d_in[12];

    char* ws = (char*)d_ws;
    size_t off = 0;
    auto alloc = [&](size_t bytes) -> void* {
        void* p = ws + off;
        off = (off + bytes + 255) & ~(size_t)255;
        return p;
    };
    int* partial   = (int*)alloc((size_t)KB * PTS * 4);          // 5.5 MB
    int* partial_T = (int*)alloc((size_t)NT * KB * 4);           // 5.4 MB
    int* base      = (int*)alloc((size_t)KB * PTS * 4);          // 5.5 MB (slice-major base table)
    int* offs      = (int*)alloc((size_t)(NB + 1) * 4);
    int* cdoffs    = (int*)alloc((size_t)(NB + 1) * 4);
    int* part      = (int*)alloc(512 * 4);
    float* sbp1    = (float*)alloc(128 * 4);
    float* sbp2    = (float*)alloc(128 * 4);
    unsigned short* wb1 = (unsigned short*)alloc((size_t)WBN * 2);
    unsigned short* wb2 = (unsigned short*)alloc((size_t)WBN * 2);
    unsigned* pp   = (unsigned*)alloc((size_t)KM * 4);           // 10.8 MB
    unsigned long long* cdesc = (unsigned long long*)alloc((size_t)CDCAP * 8);
    unsigned short* xb = (unsigned short*)alloc((size_t)N_VOX * C_CH * 2);  // 25.6 MB
    unsigned short* hb = (unsigned short*)alloc((size_t)N_VOX * C_CH * 2);  // 25.6 MB
    // total ~85 MB, no Y buffer needed

    const long TOT = (long)N_VOX * C_CH / 8 + 2 * WBN + 128;
    prep_kernel<<<(int)((TOT + 255) / 256), 256, 0, stream>>>(
        x, w1, w2, g1, b1, m1, v1, g2, b2, m2, v2,
        xb, wb1, wb2, sbp1, sbp2);

    hist_kernel<<<KB, 256, 0, stream>>>(out_map, partial);
    transp_kernel<<<14 * ((NT + 31) / 32), 256, 0, stream>>>(partial, partial_T);
    scanA_kernel<<<NBLK1, 256, 0, stream>>>(partial_T, part);
    scanB_kernel<<<2, 128, 0, stream>>>(part);
    scanC_kernel<<<NBLK1, 256, 0, stream>>>(partial_T, part, offs, cdoffs, base);
    scatter2_kernel<<<KB, 256, 0, stream>>>(in_map, out_map, base, pp);
    cdescb_kernel<<<(NB + 255) / 256, 256, 0, stream>>>(offs, cdoffs, cdesc);

    fused_kernel<0><<<NT, 1024, 0, stream>>>(xb, wb1, pp, cdesc, offs, cdoffs,
                                             sbp1, nullptr, hb);
    fused_kernel<1><<<NT, 1024, 0, stream>>>(hb, wb2, pp, cdesc, offs, cdoffs,
                                             sbp2, x, d_out);
}

// Round 15
// 397.099 us; speedup vs baseline: 1.9798x; 1.1783x over previous
//
#include <hip/hip_runtime.h>
#include <stdint.h>

// Problem constants
#define N_VOX    200000
#define C_CH     64
#define K_OFF    27
#define M_PAIRS  100000
#define KM       (K_OFF * M_PAIRS)          // 2,700,000 pairs
#define TILE     64                         // output voxels per tile (o>>6)
#define NT       (N_VOX / TILE)             // 3125 tiles exactly
#define NB       (NT * K_OFF)               // 84375 (tile,k) buckets
#define WBN      (K_OFF * 4096)             // 110592 weight elems per layer
#define EPS_BN   1e-5f
#define CDCAP    (KM / 16 + NB + 64)        // max total chunks

// slice decomposition (atomic-free sort)
#define SLICES   16
#define SLICE_LEN (M_PAIRS / SLICES)        // 6250
#define KB       (K_OFF * SLICES)           // 432
#define PTS      3200                       // plane stride (3125 padded)

// hierarchical scan geometry
#define SCHUNK   2048
#define NBLK1    ((NB + SCHUNK - 1) / SCHUNK)   // 42
#define PQ1      0
#define PQ2      128

// fused-kernel LDS capacities
#define YCAP     1040                       // rows/tile (mean 864, +6 sigma)
#define CLCAP    160                        // chunk descriptors/tile (mean ~67)

typedef __attribute__((ext_vector_type(8))) short   short8_t;  // 8 x bf16
typedef __attribute__((ext_vector_type(4))) float   f32x4;

__device__ __forceinline__ unsigned short f2bf(float f) {
    union { float f; unsigned u; } v; v.f = f;
    unsigned r = v.u + 0x7FFFu + ((v.u >> 16) & 1u);   // RTNE
    return (unsigned short)(r >> 16);
}
__device__ __forceinline__ float bf2f(unsigned u16) {
    union { unsigned u; float f; } v; v.u = u16 << 16;
    return v.f;
}
// position-layout channel index -> standard channel
__device__ __forceinline__ int pmap(int cs) {
    int p = cs >> 1, h = cs & 1;
    return (p & 3) * 16 + (p >> 2) * 2 + h;
}

// ---------- prep: xb convert (8-wide), w1 (std) / w2 (PMAP-Cin) B-frag swizzle, BN fold ----------
__global__ void prep_kernel(const float* __restrict__ x,
                            const float* __restrict__ w1, const float* __restrict__ w2,
                            const float* __restrict__ g1, const float* __restrict__ b1,
                            const float* __restrict__ m1, const float* __restrict__ v1,
                            const float* __restrict__ g2, const float* __restrict__ b2,
                            const float* __restrict__ m2, const float* __restrict__ v2,
                            unsigned short* __restrict__ xb,
                            unsigned short* __restrict__ wb1, unsigned short* __restrict__ wb2,
                            float* __restrict__ sbp1, float* __restrict__ sbp2)
{
    long i = (long)blockIdx.x * blockDim.x + threadIdx.x;
    const long XBN8 = (long)N_VOX * C_CH / 8;   // 1.6M
    if (i < XBN8) {
        const f32x4* sp = (const f32x4*)(x + (size_t)i * 8);
        f32x4 a = sp[0], b = sp[1];
        uint4 o;
        o.x = (unsigned)f2bf(a[0]) | ((unsigned)f2bf(a[1]) << 16);
        o.y = (unsigned)f2bf(a[2]) | ((unsigned)f2bf(a[3]) << 16);
        o.z = (unsigned)f2bf(b[0]) | ((unsigned)f2bf(b[1]) << 16);
        o.w = (unsigned)f2bf(b[2]) | ((unsigned)f2bf(b[3]) << 16);
        ((uint4*)xb)[i] = o;
        return;
    }
    long j = i - XBN8;
    if (j < 2 * WBN) {
        int isw2 = j >= WBN;
        int o = (int)(isw2 ? j - WBN : j);
        int k   = o >> 12;
        int rem = o & 4095;
        int t  = rem >> 11;
        int sl = (rem >> 9) & 3;
        int d  = (rem >> 3) & 63;
        int jj = rem & 7;
        int cs = t * 32 + sl * 8 + jj;      // A k-slot
        if (!isw2) wb1[o] = f2bf(w1[k * 4096 + cs * 64 + d]);
        else       wb2[o] = f2bf(w2[k * 4096 + pmap(cs) * 64 + d]);  // hb is position-permuted
        return;
    }
    j -= 2 * WBN;
    if (j < 128) {
        int L = (int)(j >= 64);
        int ch = (int)(j & 63);
        float gv = L ? g2[ch] : g1[ch];
        float vv = L ? v2[ch] : v1[ch];
        float mv = L ? m2[ch] : m1[ch];
        float bv = L ? b2[ch] : b1[ch];
        float s = gv * rsqrtf(vv + EPS_BN);
        float sh = bv - mv * s;
        int n = ch >> 4, rem = ch & 15, m = rem >> 1, h = rem & 1;
        int idx = 2 * (m * 4 + n) + h;      // position-layout slot
        float* sbp = L ? sbp2 : sbp1;
        sbp[idx] = s; sbp[64 + idx] = sh;
    }
}

// ---------- hist: per-(k,slice) block, LDS tile-histogram, coalesced partial write ----------
__global__ __launch_bounds__(256) void hist_kernel(const int* __restrict__ out_map,
                                                   int* __restrict__ partial)
{
    __shared__ int h[3136];
    int blk = blockIdx.x;                 // 432 = 27k x 16s
    int k = blk >> 4, s = blk & 15;
    int tid = threadIdx.x;
    for (int i = tid; i < 3136; i += 256) h[i] = 0;
    __syncthreads();
    int p0 = k * M_PAIRS + s * SLICE_LEN;
    for (int i = tid; i < SLICE_LEN; i += 256)
        atomicAdd(&h[out_map[p0 + i] >> 6], 1);
    __syncthreads();
    for (int t = tid; t < NT; t += 256)
        partial[blk * PTS + t] = h[t];
}

// ---------- transpose partial[kb][t] -> partial_T[t][kb] (LDS-tiled) ----------
__global__ __launch_bounds__(256) void transp_kernel(const int* __restrict__ partial,
                                                     int* __restrict__ partial_T)
{
    __shared__ int tb[32][33];
    int bx = blockIdx.x % 14, by = blockIdx.x / 14;
    int kb0 = bx * 32, t0 = by * 32;
    int tx = threadIdx.x & 31, ty = threadIdx.x >> 5;   // ty 0..7
    #pragma unroll
    for (int dy = 0; dy < 32; dy += 8) {
        int kb = kb0 + ty + dy;
        tb[ty + dy][tx] = (kb < KB) ? partial[kb * PTS + t0 + tx] : 0;
    }
    __syncthreads();
    #pragma unroll
    for (int dy = 0; dy < 32; dy += 8) {
        int t = t0 + ty + dy;
        int kb = kb0 + tx;
        if (t < NT && kb < KB)
            partial_T[t * KB + kb] = tb[tx][ty + dy];
    }
}

// ---------- scanA: per-2048-bucket partial sums (raw + ceil16) ----------
__global__ __launch_bounds__(256) void scanA_kernel(const int* __restrict__ partial_T,
                                                    int* __restrict__ part)
{
    __shared__ int lds[256], lds2[256];
    int b0 = blockIdx.x * SCHUNK;
    int t = threadIdx.x;
    int sraw = 0, sc16 = 0;
    for (int i = t; i < SCHUNK; i += 256) {
        int b = b0 + i;
        if (b < NB) {
            int tt = b / K_OFF, k = b % K_OFF;
            const int* pr = &partial_T[tt * KB + k * SLICES];
            int c = 0;
            #pragma unroll
            for (int s = 0; s < SLICES; ++s) c += pr[s];
            sraw += c; sc16 += (c + 15) >> 4;
        }
    }
    lds[t] = sraw; lds2[t] = sc16;
    __syncthreads();
    for (int d = 128; d > 0; d >>= 1) {
        if (t < d) { lds[t] += lds[t + d]; lds2[t] += lds2[t + d]; }
        __syncthreads();
    }
    if (t == 0) { part[PQ1 + blockIdx.x] = lds[0]; part[PQ2 + blockIdx.x] = lds2[0]; }
}

// ---------- scanB: exclusive scan of chunk partials (2 segments) ----------
__global__ __launch_bounds__(128) void scanB_kernel(int* __restrict__ part) {
    __shared__ int lds[128];
    int g = blockIdx.x, t = threadIdx.x;
    int base = (g == 0) ? PQ1 : PQ2;
    int v = (t < NBLK1) ? part[base + t] : 0;
    lds[t] = v;
    __syncthreads();
    for (int d = 1; d < 128; d <<= 1) {
        int u = (t >= d) ? lds[t - d] : 0;
        __syncthreads();
        lds[t] += u;
        __syncthreads();
    }
    if (t < NBLK1) part[base + t] = lds[t] - v;
}

// ---------- scanC: chunk-local scan + base -> offs/cdoffs; fused slice-major base table ----------
__global__ __launch_bounds__(256) void scanC_kernel(const int* __restrict__ partial_T,
                                                    const int* __restrict__ part,
                                                    int* __restrict__ offs,
                                                    int* __restrict__ cdoffs,
                                                    int* __restrict__ base)   // [(k*16+s)][t] (stride PTS)
{
    __shared__ int lds[256], lds2[256];
    int b = blockIdx.x, t = threadIdx.x;
    int i0 = b * SCHUNK + t * 8;
    int c[8]; int sraw = 0, sc16 = 0;
    #pragma unroll
    for (int j = 0; j < 8; ++j) {
        int idx = i0 + j;
        int tot = 0;
        if (idx < NB) {
            int tt = idx / K_OFF, k = idx - tt * K_OFF;
            const int* pr = &partial_T[tt * KB + k * SLICES];
            #pragma unroll
            for (int s = 0; s < SLICES; ++s) tot += pr[s];
        }
        c[j] = tot;
        sraw += tot; sc16 += (tot + 15) >> 4;
    }
    int vr = sraw, vc = sc16;
    lds[t] = vr; lds2[t] = vc;
    __syncthreads();
    for (int d = 1; d < 256; d <<= 1) {
        int ur = (t >= d) ? lds[t - d] : 0;
        int uc = (t >= d) ? lds2[t - d] : 0;
        __syncthreads();
        lds[t] += ur; lds2[t] += uc;
        __syncthreads();
    }
    int braw = part[PQ1 + b] + lds[t] - vr;
    int bc16 = part[PQ2 + b] + lds2[t] - vc;
    #pragma unroll
    for (int j = 0; j < 8; ++j) {
        int idx = i0 + j;
        if (idx < NB) {
            offs[idx] = braw; cdoffs[idx] = bc16;
            int tt = idx / K_OFF, k = idx - tt * K_OFF;
            const int* pr = &partial_T[tt * KB + k * SLICES];
            int run = braw;
            #pragma unroll
            for (int s = 0; s < SLICES; ++s) {
                base[(k * SLICES + s) * PTS + tt] = run;
                run += pr[s];
            }
        }
        braw += c[j]; bc16 += (c[j] + 15) >> 4;
    }
    if (b == NBLK1 - 1 && t == 255) { offs[NB] = braw; cdoffs[NB] = bc16; }
}

// ---------- scatter2: LDS-staged base row, zero global random reads ----------
__global__ __launch_bounds__(256) void scatter2_kernel(const int* __restrict__ in_map,
                                                       const int* __restrict__ out_map,
                                                       const int* __restrict__ base,
                                                       unsigned* __restrict__ pp)
{
    __shared__ int lbase[NT];                 // 12.5 KB
    __shared__ int h2[NT];                    // 12.5 KB rank counters
    int blk = blockIdx.x;
    int k = blk >> 4, s = blk & 15;
    int tid = threadIdx.x;
    const int* gb = &base[(k * SLICES + s) * PTS];
    for (int i = tid; i < NT; i += 256) { lbase[i] = gb[i]; h2[i] = 0; }
    __syncthreads();
    int p0 = k * M_PAIRS + s * SLICE_LEN;
    #pragma unroll 2
    for (int i = tid; i < SLICE_LEN; i += 256) {
        int p = p0 + i;
        int o = out_map[p];
        int t = o >> 6;
        int rank = atomicAdd(&h2[t], 1);      // LDS-only atomic
        pp[lbase[t] + rank] = (unsigned)in_map[p] | ((unsigned)(o & 63) << 18);
    }
}

// ---------- build global chunk descriptors: k | pbase<<5 | pend<<27 ----------
__global__ void cdescb_kernel(const int* __restrict__ offs, const int* __restrict__ cdoffs,
                              unsigned long long* __restrict__ cdesc)
{
    int b = blockIdx.x * 256 + threadIdx.x;
    if (b >= NB) return;
    int k = b % K_OFF;
    int c0 = cdoffs[b];
    int nchunk = cdoffs[b + 1] - c0;
    int base = offs[b];
    int end  = offs[b + 1];
    for (int i = 0; i < nchunk; ++i)
        cdesc[c0 + i] = (unsigned long long)k
                      | ((unsigned long long)(base + 16 * i) << 5)
                      | ((unsigned long long)end << 27);
}

// ---------- fused conv v2: LDS-staged pp/cdesc, contiguous chunk ranges, depth-2 pipeline, cvt_pk ----------
// 1 block per 64-voxel tile, 1024 threads (16 waves), ~145 KB LDS, 1 block/CU.
template<int LAYER>
__global__ __launch_bounds__(1024, 1) void fused_kernel(
    const unsigned short* __restrict__ xin,     // bf16 rows [N][64] (xb std / hb position-layout)
    const unsigned short* __restrict__ wb,      // pre-swizzled bf16 weights
    const unsigned* __restrict__ pp,            // iidx | oloc<<18, (tile,k)-sorted
    const unsigned long long* __restrict__ cdesc,
    const int* __restrict__ offs,
    const int* __restrict__ cdoffs,
    const float* __restrict__ sbp,              // [0:64) scale, [64:128) shift (position order)
    const float* __restrict__ xres,             // LAYER==1 residual (std layout)
    void* __restrict__ outp)                    // L0: hb (bf16 position layout); L1: f32 std
{
    __shared__ unsigned Ylds[(YCAP + 8) * 32];  // 134.1 KB (8 trash rows)
    __shared__ unsigned ppl[YCAP];              // 4.2 KB payload stage
    __shared__ unsigned long long cl[CLCAP];    // 1.3 KB chunk descriptors
    __shared__ unsigned short ridx[YCAP];
    __shared__ unsigned short rrank[YCAP];
    __shared__ unsigned char  soloc[YCAP];
    __shared__ int hist[TILE];
    __shared__ int cstart[TILE + 1];

    const int tile = blockIdx.x;
    const int tid = threadIdx.x;
    const int p0 = offs[tile * K_OFF];
    const int p1 = offs[(tile + 1) * K_OFF];
    const int c0 = cdoffs[tile * K_OFF];
    const int c1 = cdoffs[(tile + 1) * K_OFF];
    const int nch = c1 - c0;
    int nr = p1 - p0; if (nr > YCAP) nr = YCAP;

    // ---- stage cdesc + pp into LDS; rank tables ----
    for (int i = tid; i < nch && i < CLCAP; i += 1024) cl[i] = cdesc[c0 + i];
    if (tid < TILE) hist[tid] = 0;
    __syncthreads();
    for (int i = tid; i < nr; i += 1024) {
        unsigned pv = pp[p0 + i];
        ppl[i] = pv;
        int ol = (int)((pv >> 18) & 63);
        soloc[i] = (unsigned char)ol;
        rrank[i] = (unsigned short)atomicAdd(&hist[ol], 1);
    }
    __syncthreads();
    if (tid < 64) {
        int v = hist[tid];
        int s = v;
        #pragma unroll
        for (int d = 1; d < 64; d <<= 1) {
            int u = __shfl_up(s, d, 64);
            if (tid >= d) s += u;
        }
        cstart[tid] = s - v;
        if (tid == 63) cstart[64] = s;
    }
    __syncthreads();
    for (int i = tid; i < nr; i += 1024)
        ridx[cstart[soloc[i]] + rrank[i]] = (unsigned short)i;

    // ---- phase 1: contiguous chunk range per wave, depth-2 pipeline ----
    const int wid   = tid >> 6;
    const int lane  = tid & 63;
    const int r     = lane & 15;
    const int sfour = lane >> 4;
    const int par   = lane & 1;

    const int CPW = (nch + 15) >> 4;
    int w0 = wid * CPW; if (w0 > nch) w0 = nch;
    int w1 = w0 + CPW;  if (w1 > nch) w1 = nch;

    short8_t A0s[2], A1s[2];
    int yrs[2], kks[2];
    short8_t B0[4], B1[4];
    int kcur = -1;

#define ISSUE(S, CI) do {                                                     \
        int _ci = (CI);                                                       \
        if (_ci < w1) {                                                       \
            unsigned long long _d = (_ci < CLCAP) ? cl[_ci] : cdesc[c0 + _ci];\
            kks[S] = (int)(_d & 31);                                          \
            int _pbr = (int)((_d >> 5) & 0x3FFFFF) - p0;                      \
            int _per = (int)(_d >> 27) - p0;                                  \
            int _ii = _pbr + r;                                               \
            bool _real = _ii < _per;                                          \
            int _idx = _real ? _ii : _pbr;                                    \
            if (_idx >= YCAP) _idx = 0;                                       \
            unsigned _pv = ppl[_idx];                                         \
            yrs[S] = (_real && _ii < YCAP) ? _ii : (YCAP + (_ci & 7));        \
            const short8_t* _xr =                                             \
                (const short8_t*)(xin + (size_t)(_pv & 0x3FFFFu) * 64);       \
            A0s[S] = _xr[sfour];                                              \
            A1s[S] = _xr[4 + sfour];                                          \
        }                                                                     \
    } while (0)

#define CONSUME(S) do {                                                       \
        int _kk = kks[S];                                                     \
        if (_kk != kcur) {                                                    \
            kcur = _kk;                                                       \
            const short8_t* _wbk = (const short8_t*)(wb + kcur * 4096);       \
            _Pragma("unroll")                                                 \
            for (int n = 0; n < 4; ++n) {                                     \
                B0[n] = _wbk[sfour * 64 + n * 16 + r];                        \
                B1[n] = _wbk[(4 + sfour) * 64 + n * 16 + r];                  \
            }                                                                 \
        }                                                                     \
        f32x4 acc[4] = {{0,0,0,0},{0,0,0,0},{0,0,0,0},{0,0,0,0}};             \
        _Pragma("unroll")                                                     \
        for (int n = 0; n < 4; ++n) {                                         \
            acc[n] = __builtin_amdgcn_mfma_f32_16x16x32_bf16(A0s[S], B0[n], acc[n], 0, 0, 0); \
            acc[n] = __builtin_amdgcn_mfma_f32_16x16x32_bf16(A1s[S], B1[n], acc[n], 0, 0, 0); \
        }                                                                     \
        int _yr = yrs[S];                                                     \
        _Pragma("unroll")                                                     \
        for (int jj = 0; jj < 4; jj += 2) {                                   \
            uint4 _w;                                                         \
            unsigned* _wp = (unsigned*)&_w;                                   \
            _Pragma("unroll")                                                 \
            for (int n = 0; n < 4; ++n) {                                     \
                float _mine = par ? acc[n][jj + 1] : acc[n][jj];              \
                float _send = par ? acc[n][jj]     : acc[n][jj + 1];          \
                float _t = __shfl_xor(_send, 1, 64);                          \
                float _lo = par ? _t : _mine;                                 \
                float _hi = par ? _mine : _t;                                 \
                unsigned _pk;                                                 \
                asm("v_cvt_pk_bf16_f32 %0, %1, %2" : "=v"(_pk) : "v"(_lo), "v"(_hi)); \
                _wp[n] = _pk;                                                 \
            }                                                                 \
            int _Rw = sfour * 4 + jj + par;                                   \
            int _yrow = __shfl(_yr, _Rw, 64);                                 \
            *(uint4*)&Ylds[(unsigned)_yrow * 32 + (r >> 1) * 4] = _w;         \
        }                                                                     \
    } while (0)

    ISSUE(0, w0);
    ISSUE(1, w0 + 1);
    #pragma unroll 1
    for (int i = w0; i < w1; i += 2) {
        CONSUME(0); ISSUE(0, i + 2);
        if (i + 1 < w1) { CONSUME(1); ISSUE(1, i + 3); }
    }
#undef ISSUE
#undef CONSUME
    __syncthreads();

    // ---- phase 2: register sums per voxel from LDS + BN(+relu)(+residual) ----
    const int v  = tid >> 4;        // voxel 0..63
    const int q2 = tid & 15;        // u32 pair: positions 2q2, 2q2+1
    int cs0 = cstart[v], cs1 = cstart[v + 1];
    float sum[4] = {0.f, 0.f, 0.f, 0.f};
    for (int j = cs0; j < cs1; ++j) {
        int row = (int)ridx[j];
        uint2 u = *(const uint2*)&Ylds[(unsigned)row * 32 + 2 * q2];
        sum[0] += bf2f(u.x & 0xFFFFu);
        sum[1] += bf2f(u.x >> 16);
        sum[2] += bf2f(u.y & 0xFFFFu);
        sum[3] += bf2f(u.y >> 16);
    }

    const int og = tile * TILE + v;
    const float2* sc2 = (const float2*)sbp;
    const float2* sh2 = (const float2*)(sbp + 64);
    int pA = 2 * q2, pB = 2 * q2 + 1;
    float a0 = sum[0] * sc2[pA].x + sh2[pA].x;
    float a1 = sum[1] * sc2[pA].y + sh2[pA].y;
    float b0 = sum[2] * sc2[pB].x + sh2[pB].x;
    float b1 = sum[3] * sc2[pB].y + sh2[pB].y;
    if (LAYER == 0) {
        a0 = a0 > 0.f ? a0 : 0.f; a1 = a1 > 0.f ? a1 : 0.f;
        b0 = b0 > 0.f ? b0 : 0.f; b1 = b1 > 0.f ? b1 : 0.f;
        uint2 o2;
        o2.x = (unsigned)f2bf(a0) | ((unsigned)f2bf(a1) << 16);
        o2.y = (unsigned)f2bf(b0) | ((unsigned)f2bf(b1) << 16);
        *(uint2*)((unsigned*)outp + (size_t)og * 32 + 2 * q2) = o2;
    } else {
        float* out = (float*)outp;
        int chA = (pA & 3) * 16 + (pA >> 2) * 2;
        int chB = (pB & 3) * 16 + (pB >> 2) * 2;
        float2 xrA = *(const float2*)(xres + (size_t)og * 64 + chA);
        float2 xrB = *(const float2*)(xres + (size_t)og * 64 + chB);
        a0 += xrA.x; a1 += xrA.y; b0 += xrB.x; b1 += xrB.y;
        a0 = a0 > 0.f ? a0 : 0.f; a1 = a1 > 0.f ? a1 : 0.f;
        b0 = b0 > 0.f ? b0 : 0.f; b1 = b1 > 0.f ? b1 : 0.f;
        *(float2*)(out + (size_t)og * 64 + chA) = make_float2(a0, a1);
        *(float2*)(out + (size_t)og * 64 + chB) = make_float2(b0, b1);
    }
}

// ---------------- launch ----------------
extern "C" void kernel_launch(void* const* d_in, const int* in_sizes, int n_in,
                              void* d_out, int out_size, void* d_ws, size_t ws_size,
                              hipStream_t stream)
{
    const float* x  = (const float*)d_in[0];
    const float* w1 = (const float*)d_in[1];
    const float* w2 = (const float*)d_in[2];
    const float* g1 = (const float*)d_in[3];
    const float* b1 = (const float*)d_in[4];
    const float* m1 = (const float*)d_in[5];
    const float* v1 = (const float*)d_in[6];
    const float* g2 = (const float*)d_in[7];
    const float* b2 = (const float*)d_in[8];
    const float* m2 = (const float*)d_in[9];
    const float* v2 = (const float*)d_in[10];
    const int* in_map  = (const int*)d_in[11];
    const int* out_map = (const int*)d_in[12];

    char* ws = (char*)d_ws;
    size_t off = 0;
    auto alloc = [&](size_t bytes) -> void* {
        void* p = ws + off;
        off = (off + bytes + 255) & ~(size_t)255;
        return p;
    };
    int* partial   = (int*)alloc((size_t)KB * PTS * 4);          // 5.5 MB
    int* partial_T = (int*)alloc((size_t)NT * KB * 4);           // 5.4 MB
    int* base      = (int*)alloc((size_t)KB * PTS * 4);          // 5.5 MB
    int* offs      = (int*)alloc((size_t)(NB + 1) * 4);
    int* cdoffs    = (int*)alloc((size_t)(NB + 1) * 4);
    int* part      = (int*)alloc(512 * 4);
    float* sbp1    = (float*)alloc(128 * 4);
    float* sbp2    = (float*)alloc(128 * 4);
    unsigned short* wb1 = (unsigned short*)alloc((size_t)WBN * 2);
    unsigned short* wb2 = (unsigned short*)alloc((size_t)WBN * 2);
    unsigned* pp   = (unsigned*)alloc((size_t)KM * 4);           // 10.8 MB
    unsigned long long* cdesc = (unsigned long long*)alloc((size_t)CDCAP * 8);
    unsigned short* xb = (unsigned short*)alloc((size_t)N_VOX * C_CH * 2);  // 25.6 MB
    unsigned short* hb = (unsigned short*)alloc((size_t)N_VOX * C_CH * 2);  // 25.6 MB
    // total ~85 MB

    const long TOT = (long)N_VOX * C_CH / 8 + 2 * WBN + 128;
    prep_kernel<<<(int)((TOT + 255) / 256), 256, 0, stream>>>(
        x, w1, w2, g1, b1, m1, v1, g2, b2, m2, v2,
        xb, wb1, wb2, sbp1, sbp2);

    hist_kernel<<<KB, 256, 0, stream>>>(out_map, partial);
    transp_kernel<<<14 * ((NT + 31) / 32), 256, 0, stream>>>(partial, partial_T);
    scanA_kernel<<<NBLK1, 256, 0, stream>>>(partial_T, part);
    scanB_kernel<<<2, 128, 0, stream>>>(part);
    scanC_kernel<<<NBLK1, 256, 0, stream>>>(partial_T, part, offs, cdoffs, base);
    scatter2_kernel<<<KB, 256, 0, stream>>>(in_map, out_map, base, pp);
    cdescb_kernel<<<(NB + 255) / 256, 256, 0, stream>>>(offs, cdoffs, cdesc);

    fused_kernel<0><<<NT, 1024, 0, stream>>>(xb, wb1, pp, cdesc, offs, cdoffs,
                                             sbp1, nullptr, hb);
    fused_kernel<1><<<NT, 1024, 0, stream>>>(hb, wb2, pp, cdesc, offs, cdoffs,
                                             sbp2, x, d_out);
}